// Round 1
// 272.379 us; speedup vs baseline: 1.0100x; 1.0100x over previous
//
#include <hip/hip_runtime.h>

#define N_NODES 50000
#define N_EDGES 800000
#define C_IN 128
#define C_OUT 256
#define BN_EPS 1e-5f
#define NBLK ((N_NODES + 255) / 256)   // 196 scan blocks
#define SL 8                           // channel slices (== XCD count)
#define SLC 32                         // channels per slice
#define NPB 128                        // nodes per gather block (8 per 16-lane group)
#define PAD 8                          // LDS row pad (elems, keeps 16B align)

#define HB 782                         // hist/scatter blocks (1024 edges each)
#define GBX ((N_NODES + 127) / 128)    // 391 gemm row-tiles
#define GB (GBX * 4)                   // 1564 gemm blocks

using short8  = __attribute__((ext_vector_type(8))) short;
using floatx4 = __attribute__((ext_vector_type(4))) float;
using h2      = __attribute__((ext_vector_type(2))) _Float16;

union UH2 { unsigned int u; h2 h; };
union HS  { _Float16 f; unsigned short s; };

// packed f16 max -> v_pk_max_f16 (no header dependency; ROCm 7.2 lacks __hmax2)
__device__ __forceinline__ h2 pkmax(h2 a, h2 b) {
    return __builtin_elementwise_max(a, b);
}

// fp32 -> bf16 round-to-nearest-even (GEMM inputs only)
__device__ __forceinline__ unsigned short f2bf(float f) {
    unsigned int u = __float_as_uint(f);
    u = (u + 0x7fffu + ((u >> 16) & 1u)) >> 16;
    return (unsigned short)u;
}

#define XQ (N_NODES * C_IN / 4)        // 1,600,000 float4 of x
#define WQ (512 * C_IN / 4)            // 16,384 float4 of W'

// ---------------------------------------------------------------------------
// prep: fused [src-degree histogram] + [convert x->bf16, W'->bf16].
// Blocks 0..HB-1: hist (4 edges/thread, dispatched first — atomic-bound,
// overlaps the bw-bound convert). Blocks HB..: convert.
// Identity: theta@(xj-xi) + phi@xi = u[dst] + v[src]; relu/max commute so
// the edge pass only needs max over u rows.
// ---------------------------------------------------------------------------
__global__ __launch_bounds__(256) void prep(
    const float* __restrict__ x, const float* __restrict__ theta,
    const float* __restrict__ phi, const int* __restrict__ src,
    unsigned short* __restrict__ xb, unsigned short* __restrict__ wb,
    int* __restrict__ deg)
{
    const int tid = threadIdx.x;
    if (blockIdx.x < HB) {
        const int base = blockIdx.x * 1024 + tid;
        #pragma unroll
        for (int k = 0; k < 4; ++k) {
            int e = base + k * 256;
            if (e < N_EDGES) atomicAdd(&deg[src[e]], 1);
        }
        return;
    }
    int i = (blockIdx.x - HB) * 256 + tid;
    if (i < XQ) {
        float4 vv = ((const float4*)x)[i];
        ((ushort4*)xb)[i] = make_ushort4(f2bf(vv.x), f2bf(vv.y),
                                         f2bf(vv.z), f2bf(vv.w));
    } else if (i < XQ + WQ) {
        int j = i - XQ;
        float4 t;
        if (j < 256 * C_IN / 4) {
            t = ((const float4*)theta)[j];
        } else {
            int k = j - 256 * C_IN / 4;
            float4 th = ((const float4*)theta)[k];
            float4 ph = ((const float4*)phi)[k];
            t = make_float4(ph.x - th.x, ph.y - th.y, ph.z - th.z, ph.w - th.w);
        }
        ((ushort4*)wb)[j] = make_ushort4(f2bf(t.x), f2bf(t.y),
                                         f2bf(t.z), f2bf(t.w));
    }
}

// ---------------------------------------------------------------------------
// CSR scan: per-block partial sums, then scan_fin with the 196-entry
// mid-scan done redundantly per block in LDS (kills the scan_mid launch).
// ---------------------------------------------------------------------------
__global__ __launch_bounds__(256) void scan_part(
    const int* __restrict__ deg, int* __restrict__ partials)
{
    __shared__ int s[256];
    const int tid = threadIdx.x;
    int i = blockIdx.x * 256 + tid;
    s[tid] = (i < N_NODES) ? deg[i] : 0;
    __syncthreads();
    for (int d = 128; d > 0; d >>= 1) {
        if (tid < d) s[tid] += s[tid + d];
        __syncthreads();
    }
    if (tid == 0) partials[blockIdx.x] = s[0];
}

__global__ __launch_bounds__(256) void scan_fin(
    const int* __restrict__ deg, const int* __restrict__ partials,
    int* __restrict__ off, int* __restrict__ cursor)
{
    __shared__ int s[256];
    const int tid = threadIdx.x;

    // Inline mid-scan: inclusive scan of the 196 partials, redundant/block.
    int pv = (tid < NBLK) ? partials[tid] : 0;
    s[tid] = pv;
    __syncthreads();
    for (int d = 1; d < 256; d <<= 1) {
        int t = (tid >= d) ? s[tid - d] : 0;
        __syncthreads();
        s[tid] += t;
        __syncthreads();
    }
    const int blockPrefix = (blockIdx.x == 0) ? 0 : s[blockIdx.x - 1];
    const int total = s[NBLK - 1];
    __syncthreads();

    int i = blockIdx.x * 256 + tid;
    int v = (i < N_NODES) ? deg[i] : 0;
    s[tid] = v;
    __syncthreads();
    for (int d = 1; d < 256; d <<= 1) {
        int t = (tid >= d) ? s[tid - d] : 0;
        __syncthreads();
        s[tid] += t;
        __syncthreads();
    }
    int ex = s[tid] - v + blockPrefix;
    if (i < N_NODES) { off[i] = ex; cursor[i] = ex; }
    if (blockIdx.x == 0 && tid == 0) off[N_NODES] = total;
}

// ---------------------------------------------------------------------------
// gemm_scatter v3: fused [edge bucket-scatter] + [MFMA GEMM].
// A fragments direct-from-global (L2/L3-hot across the 4 by-blocks per bx),
// B staged in 34KB LDS. NEW: the C epilogue no longer issues 64 scattered
// 2B global stores per thread (104MB WRITE_SIZE = 1.9x amplification from
// 32B half-line sectors). Instead C is re-staged through the same LDS
// buffer in the exact [4 slices][128 nodes][32 ch] fp16 output image, then
// copied out with 8 contiguous dwordx4 stores/thread (4KB/round/block).
// All LDS write offsets are compile-time immediates from one base.
// Verified layouts: A-frag A[m=lane&15][k=quad*8+j]; B-frag B[k][n=lane&15];
// C/D col=lane&15, row=quad*4+reg (learn_hip m89/m91).
// ---------------------------------------------------------------------------
__global__ __launch_bounds__(256) void gemm_scatter(
    const unsigned short* __restrict__ xb,   // [N,128] bf16
    const unsigned short* __restrict__ wb,   // [512,128] bf16
    unsigned short* __restrict__ u,          // [SL][N][SLC] fp16
    unsigned short* __restrict__ v,          // [SL][N][SLC] fp16
    const int* __restrict__ src, const int* __restrict__ dst,
    int* __restrict__ cursor, int* __restrict__ edst)
{
    __shared__ unsigned short Bs[128][C_IN + PAD];   // 34816B; reused as C-stage
    const int tid = threadIdx.x;

    if (blockIdx.x < HB) {
        const int base = blockIdx.x * 1024 + tid;
        int e0 = base, e1 = base + 256, e2 = base + 512, e3 = base + 768;
        int s0 = (e0 < N_EDGES) ? src[e0] : -1;
        int s1 = (e1 < N_EDGES) ? src[e1] : -1;
        int s2 = (e2 < N_EDGES) ? src[e2] : -1;
        int s3 = (e3 < N_EDGES) ? src[e3] : -1;
        int d0 = (e0 < N_EDGES) ? dst[e0] : 0;
        int d1 = (e1 < N_EDGES) ? dst[e1] : 0;
        int d2 = (e2 < N_EDGES) ? dst[e2] : 0;
        int d3 = (e3 < N_EDGES) ? dst[e3] : 0;
        if (s0 >= 0) edst[atomicAdd(&cursor[s0], 1)] = d0;
        if (s1 >= 0) edst[atomicAdd(&cursor[s1], 1)] = d1;
        if (s2 >= 0) edst[atomicAdd(&cursor[s2], 1)] = d2;
        if (s3 >= 0) edst[atomicAdd(&cursor[s3], 1)] = d3;
        return;
    }

    const int b = blockIdx.x - HB;
    const int bx = b >> 2;
    const int by = b & 3;
    const int wave = tid >> 6;
    const int lane = tid & 63;
    const int l15 = lane & 15;
    const int quad = lane >> 4;

    // Stage B: 128 rows x 128 bf16 (2 threads/row, 8 uint4 each).
    {
        int r = tid >> 1;
        int cb = (tid & 1) * 64;
        const uint4* sp = (const uint4*)(wb + (size_t)(by * 128 + r) * C_IN + cb);
        #pragma unroll
        for (int i = 0; i < 8; ++i) *(uint4*)&Bs[r][cb + i * 8] = sp[i];
    }

    // A fragment base pointers (rows clamped; OOB rows never stored).
    const int n0 = bx * 128 + wave * 32 + l15;
    const unsigned short* arow0 = xb + (size_t)min(n0,      N_NODES - 1) * C_IN + quad * 8;
    const unsigned short* arow1 = xb + (size_t)min(n0 + 16, N_NODES - 1) * C_IN + quad * 8;

    __syncthreads();

    floatx4 acc[2][8];
    #pragma unroll
    for (int mi = 0; mi < 2; ++mi)
        #pragma unroll
        for (int ni = 0; ni < 8; ++ni)
            acc[mi][ni] = (floatx4){0.f, 0.f, 0.f, 0.f};

    #pragma unroll
    for (int ks = 0; ks < 4; ++ks) {
        short8 a[2], bfr[8];
        a[0] = *(const short8*)(arow0 + ks * 32);
        a[1] = *(const short8*)(arow1 + ks * 32);
        #pragma unroll
        for (int ni = 0; ni < 8; ++ni)
            bfr[ni] = *(const short8*)&Bs[ni * 16 + l15][ks * 32 + quad * 8];
        #pragma unroll
        for (int mi = 0; mi < 2; ++mi)
            #pragma unroll
            for (int ni = 0; ni < 8; ++ni)
                acc[mi][ni] = __builtin_amdgcn_mfma_f32_16x16x32_bf16(
                    a[mi], bfr[ni], acc[mi][ni], 0, 0, 0);
    }

    // ---- C epilogue via LDS restage ----
    __syncthreads();                       // everyone done reading Bs

    unsigned short* Cs = &Bs[0][0];        // [4][128][32] fp16 = 32KB image
    // ushort index base; mi/r/ni offsets are compile-time immediates.
    const int nbase = (wave * 32 + quad * 4) * 32 + l15;
    #pragma unroll
    for (int mi = 0; mi < 2; ++mi)
        #pragma unroll
        for (int ni = 0; ni < 8; ++ni)
            #pragma unroll
            for (int r = 0; r < 4; ++r) {
                HS hv; hv.f = (_Float16)acc[mi][ni][r];
                Cs[nbase + mi * 512 + r * 32 + (ni >> 1) * 4096 + (ni & 1) * 16] = hv.s;
            }
    __syncthreads();

    // Copy out: per round 4KB contiguous LDS -> 4KB contiguous global.
    unsigned short* base = (by < 2) ? u : v;
    const int sbase = (by & 1) * 4;        // slice base within u or v
    #pragma unroll
    for (int rr = 0; rr < 8; ++rr) {
        const int s2 = rr >> 1;
        const int n  = (rr & 1) * 64 + (tid >> 2);
        const int ob = (tid & 3) * 16;     // byte offset within 64B row
        const int ng = bx * 128 + n;
        uint4 w = *(const uint4*)((const char*)Cs + s2 * 8192 + n * 64 + ob);
        if (ng < N_NODES)
            *(uint4*)((char*)(base + ((size_t)(sbase + s2) * N_NODES + ng) * SLC) + ob) = w;
    }
}

// ---------------------------------------------------------------------------
// Sliced gather-max v2. blockIdx & 7 = channel slice = XCD: XCD s only
// touches u-slice s (3.2 MB, its-L2-resident). One node per 16-lane group.
// NEW: 16B dwordx4 gathers — lane l16 = es*4 + c4 reads the c4-th 16B chunk
// of edge-slot es's u row, so each group covers 4 edges/round (8 with the
// 2x unroll) at ~2.6x fewer instructions/byte than the 4B-gather version.
// Per-node epilogue: butterfly max over the es lanes (xor 4, 8), then each
// lane finalizes its 2 channels (c4*8 + es*2).
// ---------------------------------------------------------------------------
__global__ __launch_bounds__(256) void gather_slice(
    const int* __restrict__ off, const int* __restrict__ edst,
    const unsigned short* __restrict__ u, const unsigned short* __restrict__ v,
    float* __restrict__ out, float* __restrict__ sums, float* __restrict__ sumsq)
{
    const int slice = blockIdx.x & 7;
    const int chunk = blockIdx.x >> 3;
    const int g16 = threadIdx.x >> 4;     // block-level group id 0..15
    const int l16 = threadIdx.x & 15;
    const int es  = l16 >> 2;             // edge slot 0..3 (lane bits 2,3)
    const int c4  = l16 & 3;              // 16B chunk within 64B row
    const int c16 = c4 * 16;              // byte offset within row

    const char* ub = (const char*)(u + (size_t)slice * N_NODES * SLC);
    const unsigned short* vb = v + (size_t)slice * N_NODES * SLC;

    float s1_0 = 0.f, s1_1 = 0.f, s2_0 = 0.f, s2_1 = 0.f;

    #pragma unroll 1
    for (int i = 0; i < NPB / 16; ++i) {
        const int n = chunk * NPB + i * 16 + g16;
        if (n >= N_NODES) continue;
        const int start = off[n];
        const int end = off[n + 1];

        UH2 m0, m1, m2, m3;
        m0.u = m1.u = m2.u = m3.u = 0xFC00FC00u;   // packed f16 -inf

        const int nit = (end - start + 7) >> 3;    // 8 edges/round (clamped dups)
        const int lim = end - 1;
        int b8 = start + es;
        for (int r = 0; r < nit; ++r, b8 += 8) {
            int i0 = min(b8, lim);
            int i1 = min(b8 + 4, lim);
            int d0 = edst[i0];
            int d1 = edst[i1];
            uint4 w0 = *(const uint4*)(ub + ((d0 << 6) | c16));
            uint4 w1 = *(const uint4*)(ub + ((d1 << 6) | c16));
            UH2 a_, b_;
            a_.u = w0.x; b_.u = w1.x; m0.h = pkmax(m0.h, pkmax(a_.h, b_.h));
            a_.u = w0.y; b_.u = w1.y; m1.h = pkmax(m1.h, pkmax(a_.h, b_.h));
            a_.u = w0.z; b_.u = w1.z; m2.h = pkmax(m2.h, pkmax(a_.h, b_.h));
            a_.u = w0.w; b_.u = w1.w; m3.h = pkmax(m3.h, pkmax(a_.h, b_.h));
        }

        // Butterfly max across the 4 edge-slot lanes (lane bits 2 and 3).
        UH2 t;
        t.u = (unsigned)__shfl_xor((int)m0.u, 4); m0.h = pkmax(m0.h, t.h);
        t.u = (unsigned)__shfl_xor((int)m1.u, 4); m1.h = pkmax(m1.h, t.h);
        t.u = (unsigned)__shfl_xor((int)m2.u, 4); m2.h = pkmax(m2.h, t.h);
        t.u = (unsigned)__shfl_xor((int)m3.u, 4); m3.h = pkmax(m3.h, t.h);
        t.u = (unsigned)__shfl_xor((int)m0.u, 8); m0.h = pkmax(m0.h, t.h);
        t.u = (unsigned)__shfl_xor((int)m1.u, 8); m1.h = pkmax(m1.h, t.h);
        t.u = (unsigned)__shfl_xor((int)m2.u, 8); m2.h = pkmax(m2.h, t.h);
        t.u = (unsigned)__shfl_xor((int)m3.u, 8); m3.h = pkmax(m3.h, t.h);

        // Lane takes component es of its chunk: channels c4*8 + es*2 (+1).
        UH2 s01, s23, mm;
        s01.u = (es & 1) ? m1.u : m0.u;
        s23.u = (es & 1) ? m3.u : m2.u;
        mm.u  = (es & 2) ? s23.u : s01.u;

        const int cp = c4 * 8 + es * 2;             // channel pair offset in slice
        UH2 wv; wv.u = *(const unsigned int*)(vb + (size_t)n * SLC + cp);
        // empty node: mm = -inf -> a = 0 (matches segment_max empty -> 0)
        float a0 = fmaxf((float)wv.h[0] + (float)mm.h[0], 0.f);
        float a1 = fmaxf((float)wv.h[1] + (float)mm.h[1], 0.f);

        *(float2*)(out + (size_t)n * C_OUT + slice * SLC + cp) =
            make_float2(a0, a1);
        s1_0 += a0; s1_1 += a1;
        s2_0 += a0 * a0; s2_1 += a1 * a1;
    }

    // Stats: reduce across the 16 groups; channels are disjoint per l16
    // (channel-pair = (l16&3)*4 + (l16>>2)).
    __shared__ float red[16][16][4];
    red[g16][l16][0] = s1_0; red[g16][l16][1] = s1_1;
    red[g16][l16][2] = s2_0; red[g16][l16][3] = s2_1;
    __syncthreads();
    if (threadIdx.x < 16) {
        const int tt = threadIdx.x;
        float r0 = 0.f, r1 = 0.f, r2 = 0.f, r3 = 0.f;
        #pragma unroll
        for (int g = 0; g < 16; ++g) {
            r0 += red[g][tt][0]; r1 += red[g][tt][1];
            r2 += red[g][tt][2]; r3 += red[g][tt][3];
        }
        const int c = slice * SLC + ((tt & 3) * 4 + (tt >> 2)) * 2;
        atomicAdd(&sums[c + 0], r0);
        atomicAdd(&sums[c + 1], r1);
        atomicAdd(&sumsq[c + 0], r2);
        atomicAdd(&sumsq[c + 1], r3);
    }
}

// ---------------------------------------------------------------------------
// BN + ReLU, coefs computed redundantly per block in LDS (kills bn_prep).
// Each thread handles 4 float4 at stride 256 (all share one channel-quad).
// ---------------------------------------------------------------------------
__global__ __launch_bounds__(256) void bn_apply(
    float* __restrict__ out, const float* __restrict__ sums,
    const float* __restrict__ sumsq, const float* __restrict__ gamma,
    const float* __restrict__ beta)
{
    __shared__ float cA[C_OUT], cB[C_OUT];
    const int tid = threadIdx.x;
    {
        const float inv_n = 1.f / (float)N_NODES;
        const float mean = sums[tid] * inv_n;
        const float var = sumsq[tid] * inv_n - mean * mean;
        const float s = rsqrtf(var + BN_EPS) * gamma[tid];
        cA[tid] = s;
        cB[tid] = beta[tid] - mean * s;
    }
    __syncthreads();

    const int c4 = (tid * 4) & (C_OUT - 1);
    const float4 A = *(const float4*)(cA + c4);
    const float4 B = *(const float4*)(cB + c4);
    const int base = blockIdx.x * 1024 + tid;
    #pragma unroll
    for (int k = 0; k < 4; ++k) {
        const int i = base + k * 256;
        float4 o = ((float4*)out)[i];
        o.x = fmaxf(o.x * A.x + B.x, 0.f);
        o.y = fmaxf(o.y * A.y + B.y, 0.f);
        o.z = fmaxf(o.z * A.z + B.z, 0.f);
        o.w = fmaxf(o.w * A.w + B.w, 0.f);
        ((float4*)out)[i] = o;
    }
}

extern "C" void kernel_launch(void* const* d_in, const int* in_sizes, int n_in,
                              void* d_out, int out_size, void* d_ws, size_t ws_size,
                              hipStream_t stream) {
    const float* x     = (const float*)d_in[0];
    const int*   src   = (const int*)d_in[1];
    const int*   dst   = (const int*)d_in[2];
    const float* theta = (const float*)d_in[3];
    const float* phi   = (const float*)d_in[4];
    const float* gamma = (const float*)d_in[5];
    const float* beta  = (const float*)d_in[6];
    float* out = (float*)d_out;

    // Workspace layout (16B-aligned chunks):
    char* ws = (char*)d_ws;
    const size_t uv_elems = (size_t)N_NODES * C_OUT;
    unsigned short* u = (unsigned short*)ws;                       // 25.6 MB fp16 slice-major
    unsigned short* v = u + uv_elems;                              // 25.6 MB fp16 slice-major
    float* sums   = (float*)(v + uv_elems);
    float* sumsq  = sums + C_OUT;
    int*   deg    = (int*)(sumsq + C_OUT);                         // contiguous for one memset
    int*   off    = deg + N_NODES;                                 // N_NODES+1 entries
    int*   cursor = off + N_NODES + 4;                             // pad keeps 16B align
    int*   edst   = cursor + N_NODES;                              // 3.2 MB
    int*   partials = edst + N_EDGES;                              // NBLK ints
    unsigned short* xb = (unsigned short*)(partials + NBLK + 8);   // 12.8 MB bf16
    unsigned short* wb = xb + (size_t)N_NODES * C_IN;              // 128 KB bf16

    // Zero sums/sumsq/deg in one shot (contiguous).
    hipMemsetAsync(sums, 0, (2 * C_OUT + N_NODES) * sizeof(int), stream);

    // Fused hist + convert.
    prep<<<HB + (XQ + WQ + 255) / 256, 256, 0, stream>>>(
        x, theta, phi, src, xb, wb, deg);

    scan_part<<<NBLK, 256, 0, stream>>>(deg, partials);
    scan_fin<<<NBLK, 256, 0, stream>>>(deg, partials, off, cursor);

    // Fused scatter + MFMA GEMM (A direct-from-global, B staged in 34KB LDS).
    gemm_scatter<<<HB + GB, 256, 0, stream>>>(
        xb, wb, u, v, src, dst, cursor, edst);

    const int chunks = (N_NODES + NPB - 1) / NPB;
    gather_slice<<<chunks * SL, 256, 0, stream>>>(
        off, edst, u, v, out, sums, sumsq);

    bn_apply<<<(N_NODES * C_OUT / 4) / 1024, 256, 0, stream>>>(
        out, sums, sumsq, gamma, beta);
}

// Round 2
// 248.100 us; speedup vs baseline: 1.1088x; 1.0979x over previous
//
#include <hip/hip_runtime.h>

#define N_NODES 50000
#define N_EDGES 800000
#define C_IN 128
#define C_OUT 256
#define BN_EPS 1e-5f
#define NBLK ((N_NODES + 255) / 256)   // 196 scan blocks
#define SL 8                           // channel slices (== XCD count)
#define SLC 32                         // channels per slice
#define NPB 128                        // nodes per gather block (8 per 16-lane group)
#define PAD 8                          // LDS row pad (elems, keeps 16B align)

#define HB 782                         // hist/scatter blocks (1024 edges each)
#define GBX ((N_NODES + 127) / 128)    // 391 gemm row-tiles
#define GB (GBX * 4)                   // 1564 gemm blocks

using short8  = __attribute__((ext_vector_type(8))) short;
using floatx4 = __attribute__((ext_vector_type(4))) float;
using h2      = __attribute__((ext_vector_type(2))) _Float16;

union UH2 { unsigned int u; h2 h; };
union HS  { _Float16 f; unsigned short s; };

// packed f16 max -> v_pk_max_f16 (no header dependency; ROCm 7.2 lacks __hmax2)
__device__ __forceinline__ h2 pkmax(h2 a, h2 b) {
    return __builtin_elementwise_max(a, b);
}

// fp32 -> bf16 round-to-nearest-even (GEMM inputs only)
__device__ __forceinline__ unsigned short f2bf(float f) {
    unsigned int u = __float_as_uint(f);
    u = (u + 0x7fffu + ((u >> 16) & 1u)) >> 16;
    return (unsigned short)u;
}

#define XQ (N_NODES * C_IN / 4)        // 1,600,000 float4 of x
#define WQ (512 * C_IN / 4)            // 16,384 float4 of W'

// ---------------------------------------------------------------------------
// prep: fused [src-degree histogram + edge rank] + [convert x,W' -> bf16].
// RANK TRICK: the histogram atomicAdd's return value IS edge e's rank within
// its src segment. Storing it (coalesced) makes the later scatter atomic-free
// — we delete the second 800K-random-atomic pass entirely.
// Identity: theta@(xj-xi) + phi@xi = u[dst] + v[src]; relu/max commute so
// the edge pass only needs max over u rows.
// ---------------------------------------------------------------------------
__global__ __launch_bounds__(256) void prep(
    const float* __restrict__ x, const float* __restrict__ theta,
    const float* __restrict__ phi, const int* __restrict__ src,
    unsigned short* __restrict__ xb, unsigned short* __restrict__ wb,
    int* __restrict__ deg, int* __restrict__ rank)
{
    const int tid = threadIdx.x;
    if (blockIdx.x < HB) {
        const int base = blockIdx.x * 1024 + tid;
        #pragma unroll
        for (int k = 0; k < 4; ++k) {
            int e = base + k * 256;
            if (e < N_EDGES) rank[e] = atomicAdd(&deg[src[e]], 1);
        }
        return;
    }
    int i = (blockIdx.x - HB) * 256 + tid;
    if (i < XQ) {
        float4 vv = ((const float4*)x)[i];
        ((ushort4*)xb)[i] = make_ushort4(f2bf(vv.x), f2bf(vv.y),
                                         f2bf(vv.z), f2bf(vv.w));
    } else if (i < XQ + WQ) {
        int j = i - XQ;
        float4 t;
        if (j < 256 * C_IN / 4) {
            t = ((const float4*)theta)[j];
        } else {
            int k = j - 256 * C_IN / 4;
            float4 th = ((const float4*)theta)[k];
            float4 ph = ((const float4*)phi)[k];
            t = make_float4(ph.x - th.x, ph.y - th.y, ph.z - th.z, ph.w - th.w);
        }
        ((ushort4*)wb)[j] = make_ushort4(f2bf(t.x), f2bf(t.y),
                                         f2bf(t.z), f2bf(t.w));
    }
}

// ---------------------------------------------------------------------------
// CSR scan: per-block partial sums, then scan_fin with the 196-entry
// mid-scan done redundantly per block in LDS (kills the scan_mid launch).
// ---------------------------------------------------------------------------
__global__ __launch_bounds__(256) void scan_part(
    const int* __restrict__ deg, int* __restrict__ partials)
{
    __shared__ int s[256];
    const int tid = threadIdx.x;
    int i = blockIdx.x * 256 + tid;
    s[tid] = (i < N_NODES) ? deg[i] : 0;
    __syncthreads();
    for (int d = 128; d > 0; d >>= 1) {
        if (tid < d) s[tid] += s[tid + d];
        __syncthreads();
    }
    if (tid == 0) partials[blockIdx.x] = s[0];
}

__global__ __launch_bounds__(256) void scan_fin(
    const int* __restrict__ deg, const int* __restrict__ partials,
    int* __restrict__ off)
{
    __shared__ int s[256];
    const int tid = threadIdx.x;

    // Inline mid-scan: inclusive scan of the 196 partials, redundant/block.
    int pv = (tid < NBLK) ? partials[tid] : 0;
    s[tid] = pv;
    __syncthreads();
    for (int d = 1; d < 256; d <<= 1) {
        int t = (tid >= d) ? s[tid - d] : 0;
        __syncthreads();
        s[tid] += t;
        __syncthreads();
    }
    const int blockPrefix = (blockIdx.x == 0) ? 0 : s[blockIdx.x - 1];
    const int total = s[NBLK - 1];
    __syncthreads();

    int i = blockIdx.x * 256 + tid;
    int v = (i < N_NODES) ? deg[i] : 0;
    s[tid] = v;
    __syncthreads();
    for (int d = 1; d < 256; d <<= 1) {
        int t = (tid >= d) ? s[tid - d] : 0;
        __syncthreads();
        s[tid] += t;
        __syncthreads();
    }
    int ex = s[tid] - v + blockPrefix;
    if (i < N_NODES) off[i] = ex;
    if (blockIdx.x == 0 && tid == 0) off[N_NODES] = total;
}

// ---------------------------------------------------------------------------
// gemm_scatter v4: fused [atomic-free edge scatter] + [MFMA GEMM].
// Scatter blocks: edst[off[src[e]] + rank[e]] = dst[e] — 3 coalesced streams,
// one random 4B read of off (200KB, read-only -> L2-replicated per XCD), one
// scattered 4B write (memory-side-cache absorbed). No atomics.
// GEMM blocks: A direct-from-global (L2/L3-hot across the 4 by-blocks per
// bx), B staged in 34KB LDS, round-0 direct-store epilogue (the 2B scattered
// stores merge in L2 — verified: WRITE_SIZE identical to the coalesced
// restage variant, which only added barriers + LDS bank conflicts).
// Verified layouts: A-frag A[m=lane&15][k=quad*8+j]; B-frag B[k][n=lane&15];
// C/D col=lane&15, row=quad*4+reg (learn_hip m89/m91).
// ---------------------------------------------------------------------------
__global__ __launch_bounds__(256) void gemm_scatter(
    const unsigned short* __restrict__ xb,   // [N,128] bf16
    const unsigned short* __restrict__ wb,   // [512,128] bf16
    unsigned short* __restrict__ u,          // [SL][N][SLC] fp16
    unsigned short* __restrict__ v,          // [SL][N][SLC] fp16
    const int* __restrict__ src, const int* __restrict__ dst,
    const int* __restrict__ off, const int* __restrict__ rank,
    int* __restrict__ edst)
{
    __shared__ unsigned short Bs[128][C_IN + PAD];
    const int tid = threadIdx.x;

    if (blockIdx.x < HB) {
        const int base = blockIdx.x * 1024 + tid;
        #pragma unroll
        for (int k = 0; k < 4; ++k) {
            int e = base + k * 256;
            if (e < N_EDGES) {
                int s = src[e];
                edst[off[s] + rank[e]] = dst[e];
            }
        }
        return;
    }

    const int b = blockIdx.x - HB;
    const int bx = b >> 2;
    const int by = b & 3;
    const int wave = tid >> 6;
    const int lane = tid & 63;
    const int l15 = lane & 15;
    const int quad = lane >> 4;

    // Stage B: 128 rows x 128 bf16 (2 threads/row, 8 uint4 each).
    {
        int r = tid >> 1;
        int cb = (tid & 1) * 64;
        const uint4* sp = (const uint4*)(wb + (size_t)(by * 128 + r) * C_IN + cb);
        #pragma unroll
        for (int i = 0; i < 8; ++i) *(uint4*)&Bs[r][cb + i * 8] = sp[i];
    }

    // A fragment base pointers (rows clamped; OOB rows never stored).
    const int n0 = bx * 128 + wave * 32 + l15;
    const unsigned short* arow0 = xb + (size_t)min(n0,      N_NODES - 1) * C_IN + quad * 8;
    const unsigned short* arow1 = xb + (size_t)min(n0 + 16, N_NODES - 1) * C_IN + quad * 8;

    __syncthreads();

    floatx4 acc[2][8];
    #pragma unroll
    for (int mi = 0; mi < 2; ++mi)
        #pragma unroll
        for (int ni = 0; ni < 8; ++ni)
            acc[mi][ni] = (floatx4){0.f, 0.f, 0.f, 0.f};

    #pragma unroll
    for (int ks = 0; ks < 4; ++ks) {
        short8 a[2], bfr[8];
        a[0] = *(const short8*)(arow0 + ks * 32);
        a[1] = *(const short8*)(arow1 + ks * 32);
        #pragma unroll
        for (int ni = 0; ni < 8; ++ni)
            bfr[ni] = *(const short8*)&Bs[ni * 16 + l15][ks * 32 + quad * 8];
        #pragma unroll
        for (int mi = 0; mi < 2; ++mi)
            #pragma unroll
            for (int ni = 0; ni < 8; ++ni)
                acc[mi][ni] = __builtin_amdgcn_mfma_f32_16x16x32_bf16(
                    a[mi], bfr[ni], acc[mi][ni], 0, 0, 0);
    }

    const bool is_u = (by < 2);   // 128-col tile never straddles 256
    #pragma unroll
    for (int mi = 0; mi < 2; ++mi) {
        #pragma unroll
        for (int r = 0; r < 4; ++r) {
            int n = bx * 128 + wave * 32 + mi * 16 + quad * 4 + r;
            if (n >= N_NODES) continue;
            #pragma unroll
            for (int ni = 0; ni < 8; ++ni) {
                int c = by * 128 + ni * 16 + l15;   // 0..511
                HS hv; hv.f = (_Float16)acc[mi][ni][r];
                if (is_u) {
                    int s = c >> 5, o = c & 31;
                    u[((size_t)s * N_NODES + n) * SLC + o] = hv.s;
                } else {
                    int c2 = c - C_OUT;
                    int s = c2 >> 5, o = c2 & 31;
                    v[((size_t)s * N_NODES + n) * SLC + o] = hv.s;
                }
            }
        }
    }
}

// ---------------------------------------------------------------------------
// Sliced gather-max v2. blockIdx & 7 = channel slice = XCD: XCD s only
// touches u-slice s (3.2 MB, its-L2-resident). One node per 16-lane group.
// 16B dwordx4 gathers — lane l16 = es*4 + c4 reads the c4-th 16B chunk
// of edge-slot es's u row, so each group covers 4 edges/round (8 with the
// 2x unroll). Per-node epilogue: butterfly max over the es lanes (xor 4, 8),
// then each lane finalizes its 2 channels (c4*8 + es*2).
// ---------------------------------------------------------------------------
__global__ __launch_bounds__(256) void gather_slice(
    const int* __restrict__ off, const int* __restrict__ edst,
    const unsigned short* __restrict__ u, const unsigned short* __restrict__ v,
    float* __restrict__ out, float* __restrict__ sums, float* __restrict__ sumsq)
{
    const int slice = blockIdx.x & 7;
    const int chunk = blockIdx.x >> 3;
    const int g16 = threadIdx.x >> 4;     // block-level group id 0..15
    const int l16 = threadIdx.x & 15;
    const int es  = l16 >> 2;             // edge slot 0..3 (lane bits 2,3)
    const int c4  = l16 & 3;              // 16B chunk within 64B row
    const int c16 = c4 * 16;              // byte offset within row

    const char* ub = (const char*)(u + (size_t)slice * N_NODES * SLC);
    const unsigned short* vb = v + (size_t)slice * N_NODES * SLC;

    float s1_0 = 0.f, s1_1 = 0.f, s2_0 = 0.f, s2_1 = 0.f;

    #pragma unroll 1
    for (int i = 0; i < NPB / 16; ++i) {
        const int n = chunk * NPB + i * 16 + g16;
        if (n >= N_NODES) continue;
        const int start = off[n];
        const int end = off[n + 1];

        UH2 m0, m1, m2, m3;
        m0.u = m1.u = m2.u = m3.u = 0xFC00FC00u;   // packed f16 -inf

        const int nit = (end - start + 7) >> 3;    // 8 edges/round (clamped dups)
        const int lim = end - 1;
        int b8 = start + es;
        for (int r = 0; r < nit; ++r, b8 += 8) {
            int i0 = min(b8, lim);
            int i1 = min(b8 + 4, lim);
            int d0 = edst[i0];
            int d1 = edst[i1];
            uint4 w0 = *(const uint4*)(ub + ((d0 << 6) | c16));
            uint4 w1 = *(const uint4*)(ub + ((d1 << 6) | c16));
            UH2 a_, b_;
            a_.u = w0.x; b_.u = w1.x; m0.h = pkmax(m0.h, pkmax(a_.h, b_.h));
            a_.u = w0.y; b_.u = w1.y; m1.h = pkmax(m1.h, pkmax(a_.h, b_.h));
            a_.u = w0.z; b_.u = w1.z; m2.h = pkmax(m2.h, pkmax(a_.h, b_.h));
            a_.u = w0.w; b_.u = w1.w; m3.h = pkmax(m3.h, pkmax(a_.h, b_.h));
        }

        // Butterfly max across the 4 edge-slot lanes (lane bits 2 and 3).
        UH2 t;
        t.u = (unsigned)__shfl_xor((int)m0.u, 4); m0.h = pkmax(m0.h, t.h);
        t.u = (unsigned)__shfl_xor((int)m1.u, 4); m1.h = pkmax(m1.h, t.h);
        t.u = (unsigned)__shfl_xor((int)m2.u, 4); m2.h = pkmax(m2.h, t.h);
        t.u = (unsigned)__shfl_xor((int)m3.u, 4); m3.h = pkmax(m3.h, t.h);
        t.u = (unsigned)__shfl_xor((int)m0.u, 8); m0.h = pkmax(m0.h, t.h);
        t.u = (unsigned)__shfl_xor((int)m1.u, 8); m1.h = pkmax(m1.h, t.h);
        t.u = (unsigned)__shfl_xor((int)m2.u, 8); m2.h = pkmax(m2.h, t.h);
        t.u = (unsigned)__shfl_xor((int)m3.u, 8); m3.h = pkmax(m3.h, t.h);

        // Lane takes component es of its chunk: channels c4*8 + es*2 (+1).
        UH2 s01, s23, mm;
        s01.u = (es & 1) ? m1.u : m0.u;
        s23.u = (es & 1) ? m3.u : m2.u;
        mm.u  = (es & 2) ? s23.u : s01.u;

        const int cp = c4 * 8 + es * 2;             // channel pair offset in slice
        UH2 wv; wv.u = *(const unsigned int*)(vb + (size_t)n * SLC + cp);
        // empty node: mm = -inf -> a = 0 (matches segment_max empty -> 0)
        float a0 = fmaxf((float)wv.h[0] + (float)mm.h[0], 0.f);
        float a1 = fmaxf((float)wv.h[1] + (float)mm.h[1], 0.f);

        *(float2*)(out + (size_t)n * C_OUT + slice * SLC + cp) =
            make_float2(a0, a1);
        s1_0 += a0; s1_1 += a1;
        s2_0 += a0 * a0; s2_1 += a1 * a1;
    }

    // Stats: reduce across the 16 groups; channels are disjoint per l16
    // (channel-pair = (l16&3)*4 + (l16>>2)).
    __shared__ float red[16][16][4];
    red[g16][l16][0] = s1_0; red[g16][l16][1] = s1_1;
    red[g16][l16][2] = s2_0; red[g16][l16][3] = s2_1;
    __syncthreads();
    if (threadIdx.x < 16) {
        const int tt = threadIdx.x;
        float r0 = 0.f, r1 = 0.f, r2 = 0.f, r3 = 0.f;
        #pragma unroll
        for (int g = 0; g < 16; ++g) {
            r0 += red[g][tt][0]; r1 += red[g][tt][1];
            r2 += red[g][tt][2]; r3 += red[g][tt][3];
        }
        const int c = slice * SLC + ((tt & 3) * 4 + (tt >> 2)) * 2;
        atomicAdd(&sums[c + 0], r0);
        atomicAdd(&sums[c + 1], r1);
        atomicAdd(&sumsq[c + 0], r2);
        atomicAdd(&sumsq[c + 1], r3);
    }
}

// ---------------------------------------------------------------------------
// BN + ReLU, coefs computed redundantly per block in LDS (kills bn_prep).
// Each thread handles 4 float4 at stride 256 (all share one channel-quad).
// ---------------------------------------------------------------------------
__global__ __launch_bounds__(256) void bn_apply(
    float* __restrict__ out, const float* __restrict__ sums,
    const float* __restrict__ sumsq, const float* __restrict__ gamma,
    const float* __restrict__ beta)
{
    __shared__ float cA[C_OUT], cB[C_OUT];
    const int tid = threadIdx.x;
    {
        const float inv_n = 1.f / (float)N_NODES;
        const float mean = sums[tid] * inv_n;
        const float var = sumsq[tid] * inv_n - mean * mean;
        const float s = rsqrtf(var + BN_EPS) * gamma[tid];
        cA[tid] = s;
        cB[tid] = beta[tid] - mean * s;
    }
    __syncthreads();

    const int c4 = (tid * 4) & (C_OUT - 1);
    const float4 A = *(const float4*)(cA + c4);
    const float4 B = *(const float4*)(cB + c4);
    const int base = blockIdx.x * 1024 + tid;
    #pragma unroll
    for (int k = 0; k < 4; ++k) {
        const int i = base + k * 256;
        float4 o = ((float4*)out)[i];
        o.x = fmaxf(o.x * A.x + B.x, 0.f);
        o.y = fmaxf(o.y * A.y + B.y, 0.f);
        o.z = fmaxf(o.z * A.z + B.z, 0.f);
        o.w = fmaxf(o.w * A.w + B.w, 0.f);
        ((float4*)out)[i] = o;
    }
}

extern "C" void kernel_launch(void* const* d_in, const int* in_sizes, int n_in,
                              void* d_out, int out_size, void* d_ws, size_t ws_size,
                              hipStream_t stream) {
    const float* x     = (const float*)d_in[0];
    const int*   src   = (const int*)d_in[1];
    const int*   dst   = (const int*)d_in[2];
    const float* theta = (const float*)d_in[3];
    const float* phi   = (const float*)d_in[4];
    const float* gamma = (const float*)d_in[5];
    const float* beta  = (const float*)d_in[6];
    float* out = (float*)d_out;

    // Workspace layout (16B-aligned chunks):
    char* ws = (char*)d_ws;
    const size_t uv_elems = (size_t)N_NODES * C_OUT;
    unsigned short* u = (unsigned short*)ws;                       // 25.6 MB fp16 slice-major
    unsigned short* v = u + uv_elems;                              // 25.6 MB fp16 slice-major
    float* sums   = (float*)(v + uv_elems);
    float* sumsq  = sums + C_OUT;
    int*   deg    = (int*)(sumsq + C_OUT);                         // contiguous for one memset
    int*   off    = deg + N_NODES;                                 // N_NODES+1 entries
    int*   rank   = off + N_NODES + 4;                             // 3.2 MB (pad keeps align)
    int*   edst   = rank + N_EDGES;                                // 3.2 MB
    int*   partials = edst + N_EDGES;                              // NBLK ints
    unsigned short* xb = (unsigned short*)(partials + NBLK + 8);   // 12.8 MB bf16
    unsigned short* wb = xb + (size_t)N_NODES * C_IN;              // 128 KB bf16

    // Zero sums/sumsq/deg in one shot (contiguous).
    hipMemsetAsync(sums, 0, (2 * C_OUT + N_NODES) * sizeof(int), stream);

    // Fused hist(+rank) + convert.
    prep<<<HB + (XQ + WQ + 255) / 256, 256, 0, stream>>>(
        x, theta, phi, src, xb, wb, deg, rank);

    scan_part<<<NBLK, 256, 0, stream>>>(deg, partials);
    scan_fin<<<NBLK, 256, 0, stream>>>(deg, partials, off);

    // Fused atomic-free scatter + MFMA GEMM.
    gemm_scatter<<<HB + GB, 256, 0, stream>>>(
        xb, wb, u, v, src, dst, off, rank, edst);

    const int chunks = (N_NODES + NPB - 1) / NPB;
    gather_slice<<<chunks * SL, 256, 0, stream>>>(
        off, edst, u, v, out, sums, sumsq);

    bn_apply<<<(N_NODES * C_OUT / 4) / 1024, 256, 0, stream>>>(
        out, sums, sumsq, gamma, beta);
}

// Round 3
// 241.183 us; speedup vs baseline: 1.1406x; 1.0287x over previous
//
#include <hip/hip_runtime.h>

#define N_NODES 50000
#define N_EDGES 800000
#define C_IN 128
#define C_OUT 256
#define BN_EPS 1e-5f
#define NBLK ((N_NODES + 255) / 256)   // 196 scan blocks
#define SL 8                           // channel slices (== XCD count)
#define SLC 32                         // channels per slice
#define NPB 128                        // nodes per gather block (8 per 16-lane group)
#define PAD 8                          // LDS row pad (elems, keeps 16B align)

#define HB 782                         // hist/scatter blocks (1024 edges each)
#define GBX ((N_NODES + 127) / 128)    // 391 gemm row-tiles
#define GB (GBX * 4)                   // 1564 gemm blocks

using short8  = __attribute__((ext_vector_type(8))) short;
using floatx4 = __attribute__((ext_vector_type(4))) float;
using h2      = __attribute__((ext_vector_type(2))) _Float16;

union UH2 { unsigned int u; h2 h; };
union HS  { _Float16 f; unsigned short s; };

// packed f16 max -> v_pk_max_f16 (no header dependency; ROCm 7.2 lacks __hmax2)
__device__ __forceinline__ h2 pkmax(h2 a, h2 b) {
    return __builtin_elementwise_max(a, b);
}

// fp32 -> bf16 round-to-nearest-even (GEMM inputs only)
__device__ __forceinline__ unsigned short f2bf(float f) {
    unsigned int u = __float_as_uint(f);
    u = (u + 0x7fffu + ((u >> 16) & 1u)) >> 16;
    return (unsigned short)u;
}

#define XQ (N_NODES * C_IN / 4)        // 1,600,000 float4 of x
#define WQ (512 * C_IN / 4)            // 16,384 float4 of W'

// ---------------------------------------------------------------------------
// prep: fused [src-degree histogram + edge rank] + [convert x,W' -> bf16].
// RANK TRICK: the histogram atomicAdd's return value IS edge e's rank within
// its src segment. Storing it (coalesced) makes the later scatter atomic-free
// — we delete the second 800K-random-atomic pass entirely.
// Identity: theta@(xj-xi) + phi@xi = u[dst] + v[src]; relu/max commute so
// the edge pass only needs max over u rows.
// ---------------------------------------------------------------------------
__global__ __launch_bounds__(256) void prep(
    const float* __restrict__ x, const float* __restrict__ theta,
    const float* __restrict__ phi, const int* __restrict__ src,
    unsigned short* __restrict__ xb, unsigned short* __restrict__ wb,
    int* __restrict__ deg, int* __restrict__ rank)
{
    const int tid = threadIdx.x;
    if (blockIdx.x < HB) {
        const int base = blockIdx.x * 1024 + tid;
        #pragma unroll
        for (int k = 0; k < 4; ++k) {
            int e = base + k * 256;
            if (e < N_EDGES) rank[e] = atomicAdd(&deg[src[e]], 1);
        }
        return;
    }
    int i = (blockIdx.x - HB) * 256 + tid;
    if (i < XQ) {
        float4 vv = ((const float4*)x)[i];
        ((ushort4*)xb)[i] = make_ushort4(f2bf(vv.x), f2bf(vv.y),
                                         f2bf(vv.z), f2bf(vv.w));
    } else if (i < XQ + WQ) {
        int j = i - XQ;
        float4 t;
        if (j < 256 * C_IN / 4) {
            t = ((const float4*)theta)[j];
        } else {
            int k = j - 256 * C_IN / 4;
            float4 th = ((const float4*)theta)[k];
            float4 ph = ((const float4*)phi)[k];
            t = make_float4(ph.x - th.x, ph.y - th.y, ph.z - th.z, ph.w - th.w);
        }
        ((ushort4*)wb)[j] = make_ushort4(f2bf(t.x), f2bf(t.y),
                                         f2bf(t.z), f2bf(t.w));
    }
}

// ---------------------------------------------------------------------------
// CSR scan: per-block partial sums, then scan_fin with the 196-entry
// mid-scan done redundantly per block in LDS (kills the scan_mid launch).
// ---------------------------------------------------------------------------
__global__ __launch_bounds__(256) void scan_part(
    const int* __restrict__ deg, int* __restrict__ partials)
{
    __shared__ int s[256];
    const int tid = threadIdx.x;
    int i = blockIdx.x * 256 + tid;
    s[tid] = (i < N_NODES) ? deg[i] : 0;
    __syncthreads();
    for (int d = 128; d > 0; d >>= 1) {
        if (tid < d) s[tid] += s[tid + d];
        __syncthreads();
    }
    if (tid == 0) partials[blockIdx.x] = s[0];
}

__global__ __launch_bounds__(256) void scan_fin(
    const int* __restrict__ deg, const int* __restrict__ partials,
    int* __restrict__ off)
{
    __shared__ int s[256];
    const int tid = threadIdx.x;

    // Inline mid-scan: inclusive scan of the 196 partials, redundant/block.
    int pv = (tid < NBLK) ? partials[tid] : 0;
    s[tid] = pv;
    __syncthreads();
    for (int d = 1; d < 256; d <<= 1) {
        int t = (tid >= d) ? s[tid - d] : 0;
        __syncthreads();
        s[tid] += t;
        __syncthreads();
    }
    const int blockPrefix = (blockIdx.x == 0) ? 0 : s[blockIdx.x - 1];
    const int total = s[NBLK - 1];
    __syncthreads();

    int i = blockIdx.x * 256 + tid;
    int v = (i < N_NODES) ? deg[i] : 0;
    s[tid] = v;
    __syncthreads();
    for (int d = 1; d < 256; d <<= 1) {
        int t = (tid >= d) ? s[tid - d] : 0;
        __syncthreads();
        s[tid] += t;
        __syncthreads();
    }
    int ex = s[tid] - v + blockPrefix;
    if (i < N_NODES) off[i] = ex;
    if (blockIdx.x == 0 && tid == 0) off[N_NODES] = total;
}

// ---------------------------------------------------------------------------
// gemm_scatter v4: fused [atomic-free edge scatter] + [MFMA GEMM].
// Scatter blocks: edst[off[src[e]] + rank[e]] = dst[e] — 3 coalesced streams,
// one random 4B read of off (200KB, read-only -> L2-replicated per XCD), one
// scattered 4B write (memory-side-cache absorbed). No atomics.
// GEMM blocks: A direct-from-global (L2/L3-hot across the 4 by-blocks per
// bx), B staged in 34KB LDS, direct-store epilogue (the 2B scattered stores
// merge in L2 — verified: WRITE_SIZE identical to a coalesced LDS-restage
// variant, which only added barriers + LDS bank conflicts).
// Verified layouts: A-frag A[m=lane&15][k=quad*8+j]; B-frag B[k][n=lane&15];
// C/D col=lane&15, row=quad*4+reg (learn_hip m89/m91).
// ---------------------------------------------------------------------------
__global__ __launch_bounds__(256) void gemm_scatter(
    const unsigned short* __restrict__ xb,   // [N,128] bf16
    const unsigned short* __restrict__ wb,   // [512,128] bf16
    unsigned short* __restrict__ u,          // [SL][N][SLC] fp16
    unsigned short* __restrict__ v,          // [SL][N][SLC] fp16
    const int* __restrict__ src, const int* __restrict__ dst,
    const int* __restrict__ off, const int* __restrict__ rank,
    int* __restrict__ edst)
{
    __shared__ unsigned short Bs[128][C_IN + PAD];
    const int tid = threadIdx.x;

    if (blockIdx.x < HB) {
        const int base = blockIdx.x * 1024 + tid;
        #pragma unroll
        for (int k = 0; k < 4; ++k) {
            int e = base + k * 256;
            if (e < N_EDGES) {
                int s = src[e];
                edst[off[s] + rank[e]] = dst[e];
            }
        }
        return;
    }

    const int b = blockIdx.x - HB;
    const int bx = b >> 2;
    const int by = b & 3;
    const int wave = tid >> 6;
    const int lane = tid & 63;
    const int l15 = lane & 15;
    const int quad = lane >> 4;

    // Stage B: 128 rows x 128 bf16 (2 threads/row, 8 uint4 each).
    {
        int r = tid >> 1;
        int cb = (tid & 1) * 64;
        const uint4* sp = (const uint4*)(wb + (size_t)(by * 128 + r) * C_IN + cb);
        #pragma unroll
        for (int i = 0; i < 8; ++i) *(uint4*)&Bs[r][cb + i * 8] = sp[i];
    }

    // A fragment base pointers (rows clamped; OOB rows never stored).
    const int n0 = bx * 128 + wave * 32 + l15;
    const unsigned short* arow0 = xb + (size_t)min(n0,      N_NODES - 1) * C_IN + quad * 8;
    const unsigned short* arow1 = xb + (size_t)min(n0 + 16, N_NODES - 1) * C_IN + quad * 8;

    __syncthreads();

    floatx4 acc[2][8];
    #pragma unroll
    for (int mi = 0; mi < 2; ++mi)
        #pragma unroll
        for (int ni = 0; ni < 8; ++ni)
            acc[mi][ni] = (floatx4){0.f, 0.f, 0.f, 0.f};

    #pragma unroll
    for (int ks = 0; ks < 4; ++ks) {
        short8 a[2], bfr[8];
        a[0] = *(const short8*)(arow0 + ks * 32);
        a[1] = *(const short8*)(arow1 + ks * 32);
        #pragma unroll
        for (int ni = 0; ni < 8; ++ni)
            bfr[ni] = *(const short8*)&Bs[ni * 16 + l15][ks * 32 + quad * 8];
        #pragma unroll
        for (int mi = 0; mi < 2; ++mi)
            #pragma unroll
            for (int ni = 0; ni < 8; ++ni)
                acc[mi][ni] = __builtin_amdgcn_mfma_f32_16x16x32_bf16(
                    a[mi], bfr[ni], acc[mi][ni], 0, 0, 0);
    }

    const bool is_u = (by < 2);   // 128-col tile never straddles 256
    #pragma unroll
    for (int mi = 0; mi < 2; ++mi) {
        #pragma unroll
        for (int r = 0; r < 4; ++r) {
            int n = bx * 128 + wave * 32 + mi * 16 + quad * 4 + r;
            if (n >= N_NODES) continue;
            #pragma unroll
            for (int ni = 0; ni < 8; ++ni) {
                int c = by * 128 + ni * 16 + l15;   // 0..511
                HS hv; hv.f = (_Float16)acc[mi][ni][r];
                if (is_u) {
                    int s = c >> 5, o = c & 31;
                    u[((size_t)s * N_NODES + n) * SLC + o] = hv.s;
                } else {
                    int c2 = c - C_OUT;
                    int s = c2 >> 5, o = c2 & 31;
                    v[((size_t)s * N_NODES + n) * SLC + o] = hv.s;
                }
            }
        }
    }
}

// ---------------------------------------------------------------------------
// Sliced gather-max v3. blockIdx & 7 = channel slice = XCD: XCD s only
// touches u-slice s (3.2 MB, its-L2-resident). One node per 16-lane group,
// lane l16 = es*4 + c4 reads the c4-th 16B chunk of edge-slot es's u row.
// NEW (latency fix): 16 edges/round — each lane issues 4 independent edst
// index loads, then 4 independent 16B gathers (4-deep MLP/lane, was 2).
// Avg deg=16 -> most nodes collapse to ONE round, halving the serial
// edst->gather latency chain per node. v2 measured 67us with VALUBusy 42%,
// HBM 22%, 0 conflicts: pure unhidden-latency bound (L2 gather floor ~13us).
// Per-node epilogue: butterfly max over es lanes (xor 4, 8), then each lane
// finalizes its 2 channels (c4*8 + es*2).
// ---------------------------------------------------------------------------
__global__ __launch_bounds__(256) void gather_slice(
    const int* __restrict__ off, const int* __restrict__ edst,
    const unsigned short* __restrict__ u, const unsigned short* __restrict__ v,
    float* __restrict__ out, float* __restrict__ sums, float* __restrict__ sumsq)
{
    const int slice = blockIdx.x & 7;
    const int chunk = blockIdx.x >> 3;
    const int g16 = threadIdx.x >> 4;     // block-level group id 0..15
    const int l16 = threadIdx.x & 15;
    const int es  = l16 >> 2;             // edge slot 0..3 (lane bits 2,3)
    const int c4  = l16 & 3;              // 16B chunk within 64B row
    const int c16 = c4 * 16;              // byte offset within row

    const char* ub = (const char*)(u + (size_t)slice * N_NODES * SLC);
    const unsigned short* vb = v + (size_t)slice * N_NODES * SLC;

    float s1_0 = 0.f, s1_1 = 0.f, s2_0 = 0.f, s2_1 = 0.f;

    #pragma unroll 1
    for (int i = 0; i < NPB / 16; ++i) {
        const int n = chunk * NPB + i * 16 + g16;
        if (n >= N_NODES) continue;
        const int start = off[n];
        const int end = off[n + 1];

        UH2 m0, m1, m2, m3;
        m0.u = m1.u = m2.u = m3.u = 0xFC00FC00u;   // packed f16 -inf

        const int nit = (end - start + 15) >> 4;   // 16 edges/round (clamped dups)
        const int lim = end - 1;
        int b16 = start + es;
        for (int r = 0; r < nit; ++r, b16 += 16) {
            // 4 independent index loads (slot stride 4 covers 16 edges/group)
            int i0 = min(b16,      lim);
            int i1 = min(b16 + 4,  lim);
            int i2 = min(b16 + 8,  lim);
            int i3 = min(b16 + 12, lim);
            int d0 = edst[i0];
            int d1 = edst[i1];
            int d2 = edst[i2];
            int d3 = edst[i3];
            // 4 independent 16B gathers in flight
            uint4 w0 = *(const uint4*)(ub + ((d0 << 6) | c16));
            uint4 w1 = *(const uint4*)(ub + ((d1 << 6) | c16));
            uint4 w2 = *(const uint4*)(ub + ((d2 << 6) | c16));
            uint4 w3 = *(const uint4*)(ub + ((d3 << 6) | c16));
            UH2 a_, b_, c_, e_;
            a_.u = w0.x; b_.u = w1.x; c_.u = w2.x; e_.u = w3.x;
            m0.h = pkmax(m0.h, pkmax(pkmax(a_.h, b_.h), pkmax(c_.h, e_.h)));
            a_.u = w0.y; b_.u = w1.y; c_.u = w2.y; e_.u = w3.y;
            m1.h = pkmax(m1.h, pkmax(pkmax(a_.h, b_.h), pkmax(c_.h, e_.h)));
            a_.u = w0.z; b_.u = w1.z; c_.u = w2.z; e_.u = w3.z;
            m2.h = pkmax(m2.h, pkmax(pkmax(a_.h, b_.h), pkmax(c_.h, e_.h)));
            a_.u = w0.w; b_.u = w1.w; c_.u = w2.w; e_.u = w3.w;
            m3.h = pkmax(m3.h, pkmax(pkmax(a_.h, b_.h), pkmax(c_.h, e_.h)));
        }

        // Butterfly max across the 4 edge-slot lanes (lane bits 2 and 3).
        UH2 t;
        t.u = (unsigned)__shfl_xor((int)m0.u, 4); m0.h = pkmax(m0.h, t.h);
        t.u = (unsigned)__shfl_xor((int)m1.u, 4); m1.h = pkmax(m1.h, t.h);
        t.u = (unsigned)__shfl_xor((int)m2.u, 4); m2.h = pkmax(m2.h, t.h);
        t.u = (unsigned)__shfl_xor((int)m3.u, 4); m3.h = pkmax(m3.h, t.h);
        t.u = (unsigned)__shfl_xor((int)m0.u, 8); m0.h = pkmax(m0.h, t.h);
        t.u = (unsigned)__shfl_xor((int)m1.u, 8); m1.h = pkmax(m1.h, t.h);
        t.u = (unsigned)__shfl_xor((int)m2.u, 8); m2.h = pkmax(m2.h, t.h);
        t.u = (unsigned)__shfl_xor((int)m3.u, 8); m3.h = pkmax(m3.h, t.h);

        // Lane takes component es of its chunk: channels c4*8 + es*2 (+1).
        UH2 s01, s23, mm;
        s01.u = (es & 1) ? m1.u : m0.u;
        s23.u = (es & 1) ? m3.u : m2.u;
        mm.u  = (es & 2) ? s23.u : s01.u;

        const int cp = c4 * 8 + es * 2;             // channel pair offset in slice
        UH2 wv; wv.u = *(const unsigned int*)(vb + (size_t)n * SLC + cp);
        // empty node: mm = -inf -> a = 0 (matches segment_max empty -> 0)
        float a0 = fmaxf((float)wv.h[0] + (float)mm.h[0], 0.f);
        float a1 = fmaxf((float)wv.h[1] + (float)mm.h[1], 0.f);

        *(float2*)(out + (size_t)n * C_OUT + slice * SLC + cp) =
            make_float2(a0, a1);
        s1_0 += a0; s1_1 += a1;
        s2_0 += a0 * a0; s2_1 += a1 * a1;
    }

    // Stats: reduce across the 16 groups; channels are disjoint per l16
    // (channel-pair = (l16&3)*4 + (l16>>2)).
    __shared__ float red[16][16][4];
    red[g16][l16][0] = s1_0; red[g16][l16][1] = s1_1;
    red[g16][l16][2] = s2_0; red[g16][l16][3] = s2_1;
    __syncthreads();
    if (threadIdx.x < 16) {
        const int tt = threadIdx.x;
        float r0 = 0.f, r1 = 0.f, r2 = 0.f, r3 = 0.f;
        #pragma unroll
        for (int g = 0; g < 16; ++g) {
            r0 += red[g][tt][0]; r1 += red[g][tt][1];
            r2 += red[g][tt][2]; r3 += red[g][tt][3];
        }
        const int c = slice * SLC + ((tt & 3) * 4 + (tt >> 2)) * 2;
        atomicAdd(&sums[c + 0], r0);
        atomicAdd(&sums[c + 1], r1);
        atomicAdd(&sumsq[c + 0], r2);
        atomicAdd(&sumsq[c + 1], r3);
    }
}

// ---------------------------------------------------------------------------
// BN + ReLU, coefs computed redundantly per block in LDS (kills bn_prep).
// Each thread handles 4 float4 at stride 256 (all share one channel-quad).
// ---------------------------------------------------------------------------
__global__ __launch_bounds__(256) void bn_apply(
    float* __restrict__ out, const float* __restrict__ sums,
    const float* __restrict__ sumsq, const float* __restrict__ gamma,
    const float* __restrict__ beta)
{
    __shared__ float cA[C_OUT], cB[C_OUT];
    const int tid = threadIdx.x;
    {
        const float inv_n = 1.f / (float)N_NODES;
        const float mean = sums[tid] * inv_n;
        const float var = sumsq[tid] * inv_n - mean * mean;
        const float s = rsqrtf(var + BN_EPS) * gamma[tid];
        cA[tid] = s;
        cB[tid] = beta[tid] - mean * s;
    }
    __syncthreads();

    const int c4 = (tid * 4) & (C_OUT - 1);
    const float4 A = *(const float4*)(cA + c4);
    const float4 B = *(const float4*)(cB + c4);
    const int base = blockIdx.x * 1024 + tid;
    #pragma unroll
    for (int k = 0; k < 4; ++k) {
        const int i = base + k * 256;
        float4 o = ((float4*)out)[i];
        o.x = fmaxf(o.x * A.x + B.x, 0.f);
        o.y = fmaxf(o.y * A.y + B.y, 0.f);
        o.z = fmaxf(o.z * A.z + B.z, 0.f);
        o.w = fmaxf(o.w * A.w + B.w, 0.f);
        ((float4*)out)[i] = o;
    }
}

extern "C" void kernel_launch(void* const* d_in, const int* in_sizes, int n_in,
                              void* d_out, int out_size, void* d_ws, size_t ws_size,
                              hipStream_t stream) {
    const float* x     = (const float*)d_in[0];
    const int*   src   = (const int*)d_in[1];
    const int*   dst   = (const int*)d_in[2];
    const float* theta = (const float*)d_in[3];
    const float* phi   = (const float*)d_in[4];
    const float* gamma = (const float*)d_in[5];
    const float* beta  = (const float*)d_in[6];
    float* out = (float*)d_out;

    // Workspace layout (16B-aligned chunks):
    char* ws = (char*)d_ws;
    const size_t uv_elems = (size_t)N_NODES * C_OUT;
    unsigned short* u = (unsigned short*)ws;                       // 25.6 MB fp16 slice-major
    unsigned short* v = u + uv_elems;                              // 25.6 MB fp16 slice-major
    float* sums   = (float*)(v + uv_elems);
    float* sumsq  = sums + C_OUT;
    int*   deg    = (int*)(sumsq + C_OUT);                         // contiguous for one memset
    int*   off    = deg + N_NODES;                                 // N_NODES+1 entries
    int*   rank   = off + N_NODES + 4;                             // 3.2 MB (pad keeps align)
    int*   edst   = rank + N_EDGES;                                // 3.2 MB
    int*   partials = edst + N_EDGES;                              // NBLK ints
    unsigned short* xb = (unsigned short*)(partials + NBLK + 8);   // 12.8 MB bf16
    unsigned short* wb = xb + (size_t)N_NODES * C_IN;              // 128 KB bf16

    // Zero sums/sumsq/deg in one shot (contiguous).
    hipMemsetAsync(sums, 0, (2 * C_OUT + N_NODES) * sizeof(int), stream);

    // Fused hist(+rank) + convert.
    prep<<<HB + (XQ + WQ + 255) / 256, 256, 0, stream>>>(
        x, theta, phi, src, xb, wb, deg, rank);

    scan_part<<<NBLK, 256, 0, stream>>>(deg, partials);
    scan_fin<<<NBLK, 256, 0, stream>>>(deg, partials, off);

    // Fused atomic-free scatter + MFMA GEMM.
    gemm_scatter<<<HB + GB, 256, 0, stream>>>(
        xb, wb, u, v, src, dst, off, rank, edst);

    const int chunks = (N_NODES + NPB - 1) / NPB;
    gather_slice<<<chunks * SL, 256, 0, stream>>>(
        off, edst, u, v, out, sums, sumsq);

    bn_apply<<<(N_NODES * C_OUT / 4) / 1024, 256, 0, stream>>>(
        out, sums, sumsq, gamma, beta);
}

// Round 5
// 234.371 us; speedup vs baseline: 1.1738x; 1.0291x over previous
//
#include <hip/hip_runtime.h>

#define N_NODES 50000
#define N_EDGES 800000
#define C_IN 128
#define C_OUT 256
#define BN_EPS 1e-5f
#define NBLK ((N_NODES + 255) / 256)   // 196 scan blocks
#define SL 8                           // channel slices (== XCD count)
#define SLC 32                         // channels per slice
#define NPB 128                        // nodes per gather block (8 per 16-lane group)
#define PAD 8                          // LDS row pad (elems, keeps 16B align)
#define ECAP 3072                      // staged edges per gather block (avg 2048, 22-sigma headroom)

#define HB 782                         // hist/scatter blocks (1024 edges each)
#define GBX ((N_NODES + 127) / 128)    // 391 gemm row-tiles
#define GB (GBX * 4)                   // 1564 gemm blocks

using short8  = __attribute__((ext_vector_type(8))) short;
using floatx4 = __attribute__((ext_vector_type(4))) float;
using h2      = __attribute__((ext_vector_type(2))) _Float16;

union UH2 { unsigned int u; h2 h; };
union HS  { _Float16 f; unsigned short s; };

// packed f16 max -> v_pk_max_f16 (no header dependency; ROCm 7.2 lacks __hmax2)
__device__ __forceinline__ h2 pkmax(h2 a, h2 b) {
    return __builtin_elementwise_max(a, b);
}

// fp32 -> bf16 round-to-nearest-even (GEMM inputs only)
__device__ __forceinline__ unsigned short f2bf(float f) {
    unsigned int u = __float_as_uint(f);
    u = (u + 0x7fffu + ((u >> 16) & 1u)) >> 16;
    return (unsigned short)u;
}

#define XQ (N_NODES * C_IN / 4)        // 1,600,000 float4 of x
#define WQ (512 * C_IN / 4)            // 16,384 float4 of W'

// ---------------------------------------------------------------------------
// prep: fused [src-degree histogram + edge rank] + [convert x,W' -> bf16].
// RANK TRICK: the histogram atomicAdd's return value IS edge e's rank within
// its src segment. Storing it (coalesced) makes the later scatter atomic-free.
// Identity: theta@(xj-xi) + phi@xi = u[dst] + v[src]; relu/max commute so
// the edge pass only needs max over u rows.
// ---------------------------------------------------------------------------
__global__ __launch_bounds__(256) void prep(
    const float* __restrict__ x, const float* __restrict__ theta,
    const float* __restrict__ phi, const int* __restrict__ src,
    unsigned short* __restrict__ xb, unsigned short* __restrict__ wb,
    int* __restrict__ deg, int* __restrict__ rank)
{
    const int tid = threadIdx.x;
    if (blockIdx.x < HB) {
        const int base = blockIdx.x * 1024 + tid;
        #pragma unroll
        for (int k = 0; k < 4; ++k) {
            int e = base + k * 256;
            if (e < N_EDGES) rank[e] = atomicAdd(&deg[src[e]], 1);
        }
        return;
    }
    int i = (blockIdx.x - HB) * 256 + tid;
    if (i < XQ) {
        float4 vv = ((const float4*)x)[i];
        ((ushort4*)xb)[i] = make_ushort4(f2bf(vv.x), f2bf(vv.y),
                                         f2bf(vv.z), f2bf(vv.w));
    } else if (i < XQ + WQ) {
        int j = i - XQ;
        float4 t;
        if (j < 256 * C_IN / 4) {
            t = ((const float4*)theta)[j];
        } else {
            int k = j - 256 * C_IN / 4;
            float4 th = ((const float4*)theta)[k];
            float4 ph = ((const float4*)phi)[k];
            t = make_float4(ph.x - th.x, ph.y - th.y, ph.z - th.z, ph.w - th.w);
        }
        ((ushort4*)wb)[j] = make_ushort4(f2bf(t.x), f2bf(t.y),
                                         f2bf(t.z), f2bf(t.w));
    }
}

// ---------------------------------------------------------------------------
// CSR scan: per-block partial sums, then scan_fin with the 196-entry
// mid-scan done redundantly per block in LDS (kills the scan_mid launch).
// ---------------------------------------------------------------------------
__global__ __launch_bounds__(256) void scan_part(
    const int* __restrict__ deg, int* __restrict__ partials)
{
    __shared__ int s[256];
    const int tid = threadIdx.x;
    int i = blockIdx.x * 256 + tid;
    s[tid] = (i < N_NODES) ? deg[i] : 0;
    __syncthreads();
    for (int d = 128; d > 0; d >>= 1) {
        if (tid < d) s[tid] += s[tid + d];
        __syncthreads();
    }
    if (tid == 0) partials[blockIdx.x] = s[0];
}

__global__ __launch_bounds__(256) void scan_fin(
    const int* __restrict__ deg, const int* __restrict__ partials,
    int* __restrict__ off)
{
    __shared__ int s[256];
    const int tid = threadIdx.x;

    // Inline mid-scan: inclusive scan of the 196 partials, redundant/block.
    int pv = (tid < NBLK) ? partials[tid] : 0;
    s[tid] = pv;
    __syncthreads();
    for (int d = 1; d < 256; d <<= 1) {
        int t = (tid >= d) ? s[tid - d] : 0;
        __syncthreads();
        s[tid] += t;
        __syncthreads();
    }
    const int blockPrefix = (blockIdx.x == 0) ? 0 : s[blockIdx.x - 1];
    const int total = s[NBLK - 1];
    __syncthreads();

    int i = blockIdx.x * 256 + tid;
    int v = (i < N_NODES) ? deg[i] : 0;
    s[tid] = v;
    __syncthreads();
    for (int d = 1; d < 256; d <<= 1) {
        int t = (tid >= d) ? s[tid - d] : 0;
        __syncthreads();
        s[tid] += t;
        __syncthreads();
    }
    int ex = s[tid] - v + blockPrefix;
    if (i < N_NODES) off[i] = ex;
    if (blockIdx.x == 0 && tid == 0) off[N_NODES] = total;
}

// ---------------------------------------------------------------------------
// gemm_scatter v4: fused [atomic-free edge scatter] + [MFMA GEMM].
// Scatter blocks: edst[off[src[e]] + rank[e]] = dst[e] — 3 coalesced streams,
// one random 4B read of off (200KB, read-only -> L2-replicated per XCD), one
// scattered 4B write (memory-side-cache absorbed). No atomics.
// GEMM blocks: A direct-from-global (L2/L3-hot across the 4 by-blocks per
// bx), B staged in 34KB LDS, direct-store epilogue (the 2B scattered stores
// merge in L2 — verified round-1: WRITE_SIZE identical to a coalesced
// LDS-restage variant, which only added barriers + LDS bank conflicts).
// Verified layouts: A-frag A[m=lane&15][k=quad*8+j]; B-frag B[k][n=lane&15];
// C/D col=lane&15, row=quad*4+reg (learn_hip m89/m91).
// ---------------------------------------------------------------------------
__global__ __launch_bounds__(256) void gemm_scatter(
    const unsigned short* __restrict__ xb,   // [N,128] bf16
    const unsigned short* __restrict__ wb,   // [512,128] bf16
    unsigned short* __restrict__ u,          // [SL][N][SLC] fp16
    unsigned short* __restrict__ v,          // [SL][N][SLC] fp16
    const int* __restrict__ src, const int* __restrict__ dst,
    const int* __restrict__ off, const int* __restrict__ rank,
    int* __restrict__ edst)
{
    __shared__ unsigned short Bs[128][C_IN + PAD];
    const int tid = threadIdx.x;

    if (blockIdx.x < HB) {
        const int base = blockIdx.x * 1024 + tid;
        #pragma unroll
        for (int k = 0; k < 4; ++k) {
            int e = base + k * 256;
            if (e < N_EDGES) {
                int s = src[e];
                edst[off[s] + rank[e]] = dst[e];
            }
        }
        return;
    }

    const int b = blockIdx.x - HB;
    const int bx = b >> 2;
    const int by = b & 3;
    const int wave = tid >> 6;
    const int lane = tid & 63;
    const int l15 = lane & 15;
    const int quad = lane >> 4;

    // Stage B: 128 rows x 128 bf16 (2 threads/row, 8 uint4 each).
    {
        int r = tid >> 1;
        int cb = (tid & 1) * 64;
        const uint4* sp = (const uint4*)(wb + (size_t)(by * 128 + r) * C_IN + cb);
        #pragma unroll
        for (int i = 0; i < 8; ++i) *(uint4*)&Bs[r][cb + i * 8] = sp[i];
    }

    // A fragment base pointers (rows clamped; OOB rows never stored).
    const int n0 = bx * 128 + wave * 32 + l15;
    const unsigned short* arow0 = xb + (size_t)min(n0,      N_NODES - 1) * C_IN + quad * 8;
    const unsigned short* arow1 = xb + (size_t)min(n0 + 16, N_NODES - 1) * C_IN + quad * 8;

    __syncthreads();

    floatx4 acc[2][8];
    #pragma unroll
    for (int mi = 0; mi < 2; ++mi)
        #pragma unroll
        for (int ni = 0; ni < 8; ++ni)
            acc[mi][ni] = (floatx4){0.f, 0.f, 0.f, 0.f};

    #pragma unroll
    for (int ks = 0; ks < 4; ++ks) {
        short8 a[2], bfr[8];
        a[0] = *(const short8*)(arow0 + ks * 32);
        a[1] = *(const short8*)(arow1 + ks * 32);
        #pragma unroll
        for (int ni = 0; ni < 8; ++ni)
            bfr[ni] = *(const short8*)&Bs[ni * 16 + l15][ks * 32 + quad * 8];
        #pragma unroll
        for (int mi = 0; mi < 2; ++mi)
            #pragma unroll
            for (int ni = 0; ni < 8; ++ni)
                acc[mi][ni] = __builtin_amdgcn_mfma_f32_16x16x32_bf16(
                    a[mi], bfr[ni], acc[mi][ni], 0, 0, 0);
    }

    const bool is_u = (by < 2);   // 128-col tile never straddles 256
    #pragma unroll
    for (int mi = 0; mi < 2; ++mi) {
        #pragma unroll
        for (int r = 0; r < 4; ++r) {
            int n = bx * 128 + wave * 32 + mi * 16 + quad * 4 + r;
            if (n >= N_NODES) continue;
            #pragma unroll
            for (int ni = 0; ni < 8; ++ni) {
                int c = by * 128 + ni * 16 + l15;   // 0..511
                HS hv; hv.f = (_Float16)acc[mi][ni][r];
                if (is_u) {
                    int s = c >> 5, o = c & 31;
                    u[((size_t)s * N_NODES + n) * SLC + o] = hv.s;
                } else {
                    int c2 = c - C_OUT;
                    int s = c2 >> 5, o = c2 & 31;
                    v[((size_t)s * N_NODES + n) * SLC + o] = hv.s;
                }
            }
        }
    }
}

// ---------------------------------------------------------------------------
// Sliced gather-max v4. blockIdx & 7 = channel slice = XCD. One node per
// 16-lane group; lane l16 = es*4+c4 reads the c4-th 16B chunk of edge-slot
// es's u row; 16 edges/round, 4-deep MLP/lane (v3 structure).
// NEW (VMEM-issue fix): the block's nodes own a CONTIGUOUS edst range
// (avg 2048 entries) — stage it + the 129 off entries into LDS with
// coalesced loads. Inner-loop index fetches become ds_read_b32 (broadcast
// across the 4 chunk-lanes, conflict-free) on the otherwise-idle LDS pipe.
// v3 was TA/issue-bound: ~15 divergent VMEM instr/node ≈ 6cy each ≈ 62us
// measured with VALU 49% / HBM 24% / nothing saturated. This halves VMEM
// instr/node (~8: only u-gathers + v + out remain).
// Guard: if a chunk has > ECAP edges (22-sigma), run the identical loop
// against global edst (uniform branch, both paths compiled).
// ---------------------------------------------------------------------------
__global__ __launch_bounds__(256) void gather_slice(
    const int* __restrict__ off, const int* __restrict__ edst,
    const unsigned short* __restrict__ u, const unsigned short* __restrict__ v,
    float* __restrict__ out, float* __restrict__ sums, float* __restrict__ sumsq)
{
    __shared__ int elds[ECAP];          // 12KB staged edge-dst indices
    __shared__ int offs[NPB + 1];       // staged CSR offsets
    __shared__ float red[16][16][4];    // stats reduction

    const int slice = blockIdx.x & 7;
    const int chunk = blockIdx.x >> 3;
    const int tid = threadIdx.x;
    const int g16 = tid >> 4;           // block-level group id 0..15
    const int l16 = tid & 15;
    const int es  = l16 >> 2;           // edge slot 0..3 (lane bits 2,3)
    const int c4  = l16 & 3;            // 16B chunk within 64B row
    const int c16 = c4 * 16;            // byte offset within row
    const int cp  = c4 * 8 + es * 2;    // this thread's channel pair in slice

    const int cn   = chunk * NPB;                     // first node of chunk
    const int nend = min(cn + NPB, N_NODES);          // exclusive
    const int nloc = nend - cn;

    // Stage offs + edst range (coalesced; one barrier).
    const int s0  = off[cn];
    const int cnt = off[nend] - s0;
    for (int t = tid; t <= nloc; t += 256) offs[t] = off[cn + t];
    const bool fits = (cnt <= ECAP);
    if (fits)
        for (int t = tid; t < cnt; t += 256) elds[t] = edst[s0 + t];
    __syncthreads();

    const char* ub = (const char*)(u + (size_t)slice * N_NODES * SLC);
    const unsigned short* vb = v + (size_t)slice * N_NODES * SLC;

    float s1_0 = 0.f, s1_1 = 0.f, s2_0 = 0.f, s2_1 = 0.f;

    auto gather_all = [&](auto fetch) {
        #pragma unroll 1
        for (int i = 0; i < NPB / 16; ++i) {
            const int nl = i * 16 + g16;
            const int n = cn + nl;
            if (n >= N_NODES) continue;
            const int start = offs[nl];
            const int end   = offs[nl + 1];

            UH2 m0, m1, m2, m3;
            m0.u = m1.u = m2.u = m3.u = 0xFC00FC00u;   // packed f16 -inf

            const int nit = (end - start + 15) >> 4;   // 16 edges/round
            const int lim = end - 1;
            int b16 = start + es;
            for (int r = 0; r < nit; ++r, b16 += 16) {
                int i0 = min(b16,      lim);
                int i1 = min(b16 + 4,  lim);
                int i2 = min(b16 + 8,  lim);
                int i3 = min(b16 + 12, lim);
                int d0 = fetch(i0);
                int d1 = fetch(i1);
                int d2 = fetch(i2);
                int d3 = fetch(i3);
                uint4 w0 = *(const uint4*)(ub + ((d0 << 6) | c16));
                uint4 w1 = *(const uint4*)(ub + ((d1 << 6) | c16));
                uint4 w2 = *(const uint4*)(ub + ((d2 << 6) | c16));
                uint4 w3 = *(const uint4*)(ub + ((d3 << 6) | c16));
                UH2 a_, b_, c_, e_;
                a_.u = w0.x; b_.u = w1.x; c_.u = w2.x; e_.u = w3.x;
                m0.h = pkmax(m0.h, pkmax(pkmax(a_.h, b_.h), pkmax(c_.h, e_.h)));
                a_.u = w0.y; b_.u = w1.y; c_.u = w2.y; e_.u = w3.y;
                m1.h = pkmax(m1.h, pkmax(pkmax(a_.h, b_.h), pkmax(c_.h, e_.h)));
                a_.u = w0.z; b_.u = w1.z; c_.u = w2.z; e_.u = w3.z;
                m2.h = pkmax(m2.h, pkmax(pkmax(a_.h, b_.h), pkmax(c_.h, e_.h)));
                a_.u = w0.w; b_.u = w1.w; c_.u = w2.w; e_.u = w3.w;
                m3.h = pkmax(m3.h, pkmax(pkmax(a_.h, b_.h), pkmax(c_.h, e_.h)));
            }

            // Butterfly max across the 4 edge-slot lanes (lane bits 2, 3).
            UH2 t;
            t.u = (unsigned)__shfl_xor((int)m0.u, 4); m0.h = pkmax(m0.h, t.h);
            t.u = (unsigned)__shfl_xor((int)m1.u, 4); m1.h = pkmax(m1.h, t.h);
            t.u = (unsigned)__shfl_xor((int)m2.u, 4); m2.h = pkmax(m2.h, t.h);
            t.u = (unsigned)__shfl_xor((int)m3.u, 4); m3.h = pkmax(m3.h, t.h);
            t.u = (unsigned)__shfl_xor((int)m0.u, 8); m0.h = pkmax(m0.h, t.h);
            t.u = (unsigned)__shfl_xor((int)m1.u, 8); m1.h = pkmax(m1.h, t.h);
            t.u = (unsigned)__shfl_xor((int)m2.u, 8); m2.h = pkmax(m2.h, t.h);
            t.u = (unsigned)__shfl_xor((int)m3.u, 8); m3.h = pkmax(m3.h, t.h);

            // Lane takes component es of its chunk: channels c4*8 + es*2.
            UH2 s01, s23, mm;
            s01.u = (es & 1) ? m1.u : m0.u;
            s23.u = (es & 1) ? m3.u : m2.u;
            mm.u  = (es & 2) ? s23.u : s01.u;

            UH2 wv; wv.u = *(const unsigned int*)(vb + (size_t)n * SLC + cp);
            // empty node: mm = -inf -> a = 0 (matches segment_max empty -> 0)
            float a0 = fmaxf((float)wv.h[0] + (float)mm.h[0], 0.f);
            float a1 = fmaxf((float)wv.h[1] + (float)mm.h[1], 0.f);

            *(float2*)(out + (size_t)n * C_OUT + slice * SLC + cp) =
                make_float2(a0, a1);
            s1_0 += a0; s1_1 += a1;
            s2_0 += a0 * a0; s2_1 += a1 * a1;
        }
    };

    if (fits) gather_all([&](int i) { return elds[i - s0]; });
    else      gather_all([&](int i) { return edst[i]; });

    // Stats: reduce across the 16 groups; channels are disjoint per l16
    // (channel-pair = (l16&3)*8 + (l16>>2)*2).
    __syncthreads();
    red[g16][l16][0] = s1_0; red[g16][l16][1] = s1_1;
    red[g16][l16][2] = s2_0; red[g16][l16][3] = s2_1;
    __syncthreads();
    if (tid < 16) {
        const int tt = tid;
        float r0 = 0.f, r1 = 0.f, r2 = 0.f, r3 = 0.f;
        #pragma unroll
        for (int g = 0; g < 16; ++g) {
            r0 += red[g][tt][0]; r1 += red[g][tt][1];
            r2 += red[g][tt][2]; r3 += red[g][tt][3];
        }
        const int c = slice * SLC + ((tt & 3) * 8 + (tt >> 2) * 2);
        atomicAdd(&sums[c + 0], r0);
        atomicAdd(&sums[c + 1], r1);
        atomicAdd(&sumsq[c + 0], r2);
        atomicAdd(&sumsq[c + 1], r3);
    }
}

// ---------------------------------------------------------------------------
// BN + ReLU, coefs computed redundantly per block in LDS (kills bn_prep).
// Each thread handles 4 float4 at stride 256 (all share one channel-quad).
// ---------------------------------------------------------------------------
__global__ __launch_bounds__(256) void bn_apply(
    float* __restrict__ out, const float* __restrict__ sums,
    const float* __restrict__ sumsq, const float* __restrict__ gamma,
    const float* __restrict__ beta)
{
    __shared__ float cA[C_OUT], cB[C_OUT];
    const int tid = threadIdx.x;
    {
        const float inv_n = 1.f / (float)N_NODES;
        const float mean = sums[tid] * inv_n;
        const float var = sumsq[tid] * inv_n - mean * mean;
        const float s = rsqrtf(var + BN_EPS) * gamma[tid];
        cA[tid] = s;
        cB[tid] = beta[tid] - mean * s;
    }
    __syncthreads();

    const int c4 = (tid * 4) & (C_OUT - 1);
    const float4 A = *(const float4*)(cA + c4);
    const float4 B = *(const float4*)(cB + c4);
    const int base = blockIdx.x * 1024 + tid;
    #pragma unroll
    for (int k = 0; k < 4; ++k) {
        const int i = base + k * 256;
        float4 o = ((float4*)out)[i];
        o.x = fmaxf(o.x * A.x + B.x, 0.f);
        o.y = fmaxf(o.y * A.y + B.y, 0.f);
        o.z = fmaxf(o.z * A.z + B.z, 0.f);
        o.w = fmaxf(o.w * A.w + B.w, 0.f);
        ((float4*)out)[i] = o;
    }
}

extern "C" void kernel_launch(void* const* d_in, const int* in_sizes, int n_in,
                              void* d_out, int out_size, void* d_ws, size_t ws_size,
                              hipStream_t stream) {
    const float* x     = (const float*)d_in[0];
    const int*   src   = (const int*)d_in[1];
    const int*   dst   = (const int*)d_in[2];
    const float* theta = (const float*)d_in[3];
    const float* phi   = (const float*)d_in[4];
    const float* gamma = (const float*)d_in[5];
    const float* beta  = (const float*)d_in[6];
    float* out = (float*)d_out;

    // Workspace layout (16B-aligned chunks):
    char* ws = (char*)d_ws;
    const size_t uv_elems = (size_t)N_NODES * C_OUT;
    unsigned short* u = (unsigned short*)ws;                       // 25.6 MB fp16 slice-major
    unsigned short* v = u + uv_elems;                              // 25.6 MB fp16 slice-major
    float* sums   = (float*)(v + uv_elems);
    float* sumsq  = sums + C_OUT;
    int*   deg    = (int*)(sumsq + C_OUT);                         // contiguous for one memset
    int*   off    = deg + N_NODES;                                 // N_NODES+1 entries
    int*   rank   = off + N_NODES + 4;                             // 3.2 MB (pad keeps align)
    int*   edst   = rank + N_EDGES;                                // 3.2 MB
    int*   partials = edst + N_EDGES;                              // NBLK ints
    unsigned short* xb = (unsigned short*)(partials + NBLK + 8);   // 12.8 MB bf16
    unsigned short* wb = xb + (size_t)N_NODES * C_IN;              // 128 KB bf16

    // Zero sums/sumsq/deg in one shot (contiguous).
    hipMemsetAsync(sums, 0, (2 * C_OUT + N_NODES) * sizeof(int), stream);

    // Fused hist(+rank) + convert.
    prep<<<HB + (XQ + WQ + 255) / 256, 256, 0, stream>>>(
        x, theta, phi, src, xb, wb, deg, rank);

    scan_part<<<NBLK, 256, 0, stream>>>(deg, partials);
    scan_fin<<<NBLK, 256, 0, stream>>>(deg, partials, off);

    // Fused atomic-free scatter + MFMA GEMM.
    gemm_scatter<<<HB + GB, 256, 0, stream>>>(
        xb, wb, u, v, src, dst, off, rank, edst);

    const int chunks = (N_NODES + NPB - 1) / NPB;
    gather_slice<<<chunks * SL, 256, 0, stream>>>(
        off, edst, u, v, out, sums, sumsq);

    bn_apply<<<(N_NODES * C_OUT / 4) / 1024, 256, 0, stream>>>(
        out, sums, sumsq, gamma, beta);
}

// Round 6
// 229.201 us; speedup vs baseline: 1.2002x; 1.0226x over previous
//
#include <hip/hip_runtime.h>

#define N_NODES 50000
#define N_EDGES 800000
#define C_IN 128
#define C_OUT 256
#define BN_EPS 1e-5f
#define NBLK ((N_NODES + 255) / 256)   // 196 scan blocks
#define SL 8                           // channel slices (== XCD count)
#define SLC 32                         // channels per slice
#define NPB 128                        // nodes per gather block (8 per 16-lane group)
#define PAD 8                          // LDS row pad (elems, keeps 16B align)
#define ECAP 3072                      // staged edges per gather block (avg 2048, 22-sigma headroom)

#define HB 782                         // hist/scatter blocks (1024 edges each)
#define GBX ((N_NODES + 127) / 128)    // 391 gemm row-tiles
#define GB (GBX * 4)                   // 1564 gemm blocks

using short8  = __attribute__((ext_vector_type(8))) short;
using floatx4 = __attribute__((ext_vector_type(4))) float;
using h2      = __attribute__((ext_vector_type(2))) _Float16;

union UH2 { unsigned int u; h2 h; };
union HS  { _Float16 f; unsigned short s; };

// packed f16 max -> v_pk_max_f16 (no header dependency; ROCm 7.2 lacks __hmax2)
__device__ __forceinline__ h2 pkmax(h2 a, h2 b) {
    return __builtin_elementwise_max(a, b);
}

// fp32 -> bf16 round-to-nearest-even (GEMM inputs only)
__device__ __forceinline__ unsigned short f2bf(float f) {
    unsigned int u = __float_as_uint(f);
    u = (u + 0x7fffu + ((u >> 16) & 1u)) >> 16;
    return (unsigned short)u;
}

#define XQ (N_NODES * C_IN / 4)        // 1,600,000 float4 of x
#define WQ (512 * C_IN / 4)            // 16,384 float4 of W'

// ---------------------------------------------------------------------------
// prep: fused [src-degree histogram + edge rank] + [convert x,W' -> bf16].
// RANK TRICK: the histogram atomicAdd's return value IS edge e's rank within
// its src segment. rank stored as ushort (max deg << 65536) — halves traffic.
// Identity: theta@(xj-xi) + phi@xi = u[dst] + v[src]; relu/max commute so
// the edge pass only needs max over u rows.
// ---------------------------------------------------------------------------
__global__ __launch_bounds__(256) void prep(
    const float* __restrict__ x, const float* __restrict__ theta,
    const float* __restrict__ phi, const int* __restrict__ src,
    unsigned short* __restrict__ xb, unsigned short* __restrict__ wb,
    int* __restrict__ deg, unsigned short* __restrict__ rank)
{
    const int tid = threadIdx.x;
    if (blockIdx.x < HB) {
        const int base = blockIdx.x * 1024 + tid;
        #pragma unroll
        for (int k = 0; k < 4; ++k) {
            int e = base + k * 256;
            if (e < N_EDGES)
                rank[e] = (unsigned short)atomicAdd(&deg[src[e]], 1);
        }
        return;
    }
    int i = (blockIdx.x - HB) * 256 + tid;
    if (i < XQ) {
        float4 vv = ((const float4*)x)[i];
        ((ushort4*)xb)[i] = make_ushort4(f2bf(vv.x), f2bf(vv.y),
                                         f2bf(vv.z), f2bf(vv.w));
    } else if (i < XQ + WQ) {
        int j = i - XQ;
        float4 t;
        if (j < 256 * C_IN / 4) {
            t = ((const float4*)theta)[j];
        } else {
            int k = j - 256 * C_IN / 4;
            float4 th = ((const float4*)theta)[k];
            float4 ph = ((const float4*)phi)[k];
            t = make_float4(ph.x - th.x, ph.y - th.y, ph.z - th.z, ph.w - th.w);
        }
        ((ushort4*)wb)[j] = make_ushort4(f2bf(t.x), f2bf(t.y),
                                         f2bf(t.z), f2bf(t.w));
    }
}

// ---------------------------------------------------------------------------
// CSR scan: per-block partial sums, then scan_fin with the 196-entry
// mid-scan done redundantly per block in LDS (kills the scan_mid launch).
// ---------------------------------------------------------------------------
__global__ __launch_bounds__(256) void scan_part(
    const int* __restrict__ deg, int* __restrict__ partials)
{
    __shared__ int s[256];
    const int tid = threadIdx.x;
    int i = blockIdx.x * 256 + tid;
    s[tid] = (i < N_NODES) ? deg[i] : 0;
    __syncthreads();
    for (int d = 128; d > 0; d >>= 1) {
        if (tid < d) s[tid] += s[tid + d];
        __syncthreads();
    }
    if (tid == 0) partials[blockIdx.x] = s[0];
}

__global__ __launch_bounds__(256) void scan_fin(
    const int* __restrict__ deg, const int* __restrict__ partials,
    int* __restrict__ off)
{
    __shared__ int s[256];
    const int tid = threadIdx.x;

    // Inline mid-scan: inclusive scan of the 196 partials, redundant/block.
    int pv = (tid < NBLK) ? partials[tid] : 0;
    s[tid] = pv;
    __syncthreads();
    for (int d = 1; d < 256; d <<= 1) {
        int t = (tid >= d) ? s[tid - d] : 0;
        __syncthreads();
        s[tid] += t;
        __syncthreads();
    }
    const int blockPrefix = (blockIdx.x == 0) ? 0 : s[blockIdx.x - 1];
    const int total = s[NBLK - 1];
    __syncthreads();

    int i = blockIdx.x * 256 + tid;
    int v = (i < N_NODES) ? deg[i] : 0;
    s[tid] = v;
    __syncthreads();
    for (int d = 1; d < 256; d <<= 1) {
        int t = (tid >= d) ? s[tid - d] : 0;
        __syncthreads();
        s[tid] += t;
        __syncthreads();
    }
    int ex = s[tid] - v + blockPrefix;
    if (i < N_NODES) off[i] = ex;
    if (blockIdx.x == 0 && tid == 0) off[N_NODES] = total;
}

// ---------------------------------------------------------------------------
// gemm_scatter v5: fused [atomic-free edge scatter] + [MFMA GEMM].
// Scatter blocks: edst[off[src[e]] + rank[e]] = (ushort)dst[e] — coalesced
// streams + one random ushort write. edst now ushort (1.6MB): halves the
// dirtied-line footprint that round-1 measured as ~50MB write amplification
// (u/v streaming writes thrash L2 and evict partially-filled edst lines).
// GEMM blocks: A direct-from-global (L2/L3-hot across the 4 by-blocks per
// bx), B staged in 34KB LDS, direct-store epilogue (2B scattered stores
// merge in L2 — verified round-1).
// Verified layouts: A-frag A[m=lane&15][k=quad*8+j]; B-frag B[k][n=lane&15];
// C/D col=lane&15, row=quad*4+reg (learn_hip m89/m91).
// ---------------------------------------------------------------------------
__global__ __launch_bounds__(256) void gemm_scatter(
    const unsigned short* __restrict__ xb,   // [N,128] bf16
    const unsigned short* __restrict__ wb,   // [512,128] bf16
    unsigned short* __restrict__ u,          // [SL][N][SLC] fp16
    unsigned short* __restrict__ v,          // [SL][N][SLC] fp16
    const int* __restrict__ src, const int* __restrict__ dst,
    const int* __restrict__ off, const unsigned short* __restrict__ rank,
    unsigned short* __restrict__ edst)
{
    __shared__ unsigned short Bs[128][C_IN + PAD];
    const int tid = threadIdx.x;

    if (blockIdx.x < HB) {
        const int base = blockIdx.x * 1024 + tid;
        #pragma unroll
        for (int k = 0; k < 4; ++k) {
            int e = base + k * 256;
            if (e < N_EDGES) {
                int s = src[e];
                edst[off[s] + (int)rank[e]] = (unsigned short)dst[e];
            }
        }
        return;
    }

    const int b = blockIdx.x - HB;
    const int bx = b >> 2;
    const int by = b & 3;
    const int wave = tid >> 6;
    const int lane = tid & 63;
    const int l15 = lane & 15;
    const int quad = lane >> 4;

    // Stage B: 128 rows x 128 bf16 (2 threads/row, 8 uint4 each).
    {
        int r = tid >> 1;
        int cb = (tid & 1) * 64;
        const uint4* sp = (const uint4*)(wb + (size_t)(by * 128 + r) * C_IN + cb);
        #pragma unroll
        for (int i = 0; i < 8; ++i) *(uint4*)&Bs[r][cb + i * 8] = sp[i];
    }

    // A fragment base pointers (rows clamped; OOB rows never stored).
    const int n0 = bx * 128 + wave * 32 + l15;
    const unsigned short* arow0 = xb + (size_t)min(n0,      N_NODES - 1) * C_IN + quad * 8;
    const unsigned short* arow1 = xb + (size_t)min(n0 + 16, N_NODES - 1) * C_IN + quad * 8;

    __syncthreads();

    floatx4 acc[2][8];
    #pragma unroll
    for (int mi = 0; mi < 2; ++mi)
        #pragma unroll
        for (int ni = 0; ni < 8; ++ni)
            acc[mi][ni] = (floatx4){0.f, 0.f, 0.f, 0.f};

    #pragma unroll
    for (int ks = 0; ks < 4; ++ks) {
        short8 a[2], bfr[8];
        a[0] = *(const short8*)(arow0 + ks * 32);
        a[1] = *(const short8*)(arow1 + ks * 32);
        #pragma unroll
        for (int ni = 0; ni < 8; ++ni)
            bfr[ni] = *(const short8*)&Bs[ni * 16 + l15][ks * 32 + quad * 8];
        #pragma unroll
        for (int mi = 0; mi < 2; ++mi)
            #pragma unroll
            for (int ni = 0; ni < 8; ++ni)
                acc[mi][ni] = __builtin_amdgcn_mfma_f32_16x16x32_bf16(
                    a[mi], bfr[ni], acc[mi][ni], 0, 0, 0);
    }

    const bool is_u = (by < 2);   // 128-col tile never straddles 256
    #pragma unroll
    for (int mi = 0; mi < 2; ++mi) {
        #pragma unroll
        for (int r = 0; r < 4; ++r) {
            int n = bx * 128 + wave * 32 + mi * 16 + quad * 4 + r;
            if (n >= N_NODES) continue;
            #pragma unroll
            for (int ni = 0; ni < 8; ++ni) {
                int c = by * 128 + ni * 16 + l15;   // 0..511
                HS hv; hv.f = (_Float16)acc[mi][ni][r];
                if (is_u) {
                    int s = c >> 5, o = c & 31;
                    u[((size_t)s * N_NODES + n) * SLC + o] = hv.s;
                } else {
                    int c2 = c - C_OUT;
                    int s = c2 >> 5, o = c2 & 31;
                    v[((size_t)s * N_NODES + n) * SLC + o] = hv.s;
                }
            }
        }
    }
}

// ---------------------------------------------------------------------------
// Sliced gather-max v5. blockIdx & 7 = channel slice = XCD. One node per
// 16-lane group; lane l16 = es*4+c4 reads the c4-th 16B chunk of edge-slot
// es's u row; 16 edges/round, 4-deep MLP/lane; block-contiguous edst range
// staged in LDS (now ushort: 6KB).
// NEW: the pre-BN aggregate relu(max_u + v) is written back IN-PLACE into
// v's just-read address as packed f16 (4B to an L1-hot line) instead of 8B
// fp32 to cold `out`. v becomes the agg buffer for bn_apply; gather's store
// traffic halves (51.2 -> 25.6 MB) and out is written only once, by bn.
// Stats still accumulate from the f32 values (f16 store rounding ~5e-4 rel).
// ---------------------------------------------------------------------------
__global__ __launch_bounds__(256) void gather_slice(
    const int* __restrict__ off, const unsigned short* __restrict__ edst,
    const unsigned short* __restrict__ u, unsigned short* __restrict__ v,
    float* __restrict__ sums, float* __restrict__ sumsq)
{
    __shared__ unsigned short elds[ECAP];   // 6KB staged edge-dst indices
    __shared__ int offs[NPB + 1];           // staged CSR offsets
    __shared__ float red[16][16][4];        // stats reduction

    const int slice = blockIdx.x & 7;
    const int chunk = blockIdx.x >> 3;
    const int tid = threadIdx.x;
    const int g16 = tid >> 4;           // block-level group id 0..15
    const int l16 = tid & 15;
    const int es  = l16 >> 2;           // edge slot 0..3 (lane bits 2,3)
    const int c4  = l16 & 3;            // 16B chunk within 64B row
    const int c16 = c4 * 16;            // byte offset within row
    const int cp  = c4 * 8 + es * 2;    // this thread's channel pair in slice

    const int cn   = chunk * NPB;                     // first node of chunk
    const int nend = min(cn + NPB, N_NODES);          // exclusive
    const int nloc = nend - cn;

    // Stage offs + edst range (coalesced; one barrier).
    const int s0  = off[cn];
    const int cnt = off[nend] - s0;
    for (int t = tid; t <= nloc; t += 256) offs[t] = off[cn + t];
    const bool fits = (cnt <= ECAP);
    if (fits)
        for (int t = tid; t < cnt; t += 256) elds[t] = edst[s0 + t];
    __syncthreads();

    const char* ub = (const char*)(u + (size_t)slice * N_NODES * SLC);
    unsigned short* vb = v + (size_t)slice * N_NODES * SLC;

    float s1_0 = 0.f, s1_1 = 0.f, s2_0 = 0.f, s2_1 = 0.f;

    auto gather_all = [&](auto fetch) {
        #pragma unroll 1
        for (int i = 0; i < NPB / 16; ++i) {
            const int nl = i * 16 + g16;
            const int n = cn + nl;
            if (n >= N_NODES) continue;
            const int start = offs[nl];
            const int end   = offs[nl + 1];

            UH2 m0, m1, m2, m3;
            m0.u = m1.u = m2.u = m3.u = 0xFC00FC00u;   // packed f16 -inf

            const int nit = (end - start + 15) >> 4;   // 16 edges/round
            const int lim = end - 1;
            int b16 = start + es;
            for (int r = 0; r < nit; ++r, b16 += 16) {
                int i0 = min(b16,      lim);
                int i1 = min(b16 + 4,  lim);
                int i2 = min(b16 + 8,  lim);
                int i3 = min(b16 + 12, lim);
                int d0 = fetch(i0);
                int d1 = fetch(i1);
                int d2 = fetch(i2);
                int d3 = fetch(i3);
                uint4 w0 = *(const uint4*)(ub + ((d0 << 6) | c16));
                uint4 w1 = *(const uint4*)(ub + ((d1 << 6) | c16));
                uint4 w2 = *(const uint4*)(ub + ((d2 << 6) | c16));
                uint4 w3 = *(const uint4*)(ub + ((d3 << 6) | c16));
                UH2 a_, b_, c_, e_;
                a_.u = w0.x; b_.u = w1.x; c_.u = w2.x; e_.u = w3.x;
                m0.h = pkmax(m0.h, pkmax(pkmax(a_.h, b_.h), pkmax(c_.h, e_.h)));
                a_.u = w0.y; b_.u = w1.y; c_.u = w2.y; e_.u = w3.y;
                m1.h = pkmax(m1.h, pkmax(pkmax(a_.h, b_.h), pkmax(c_.h, e_.h)));
                a_.u = w0.z; b_.u = w1.z; c_.u = w2.z; e_.u = w3.z;
                m2.h = pkmax(m2.h, pkmax(pkmax(a_.h, b_.h), pkmax(c_.h, e_.h)));
                a_.u = w0.w; b_.u = w1.w; c_.u = w2.w; e_.u = w3.w;
                m3.h = pkmax(m3.h, pkmax(pkmax(a_.h, b_.h), pkmax(c_.h, e_.h)));
            }

            // Butterfly max across the 4 edge-slot lanes (lane bits 2, 3).
            UH2 t;
            t.u = (unsigned)__shfl_xor((int)m0.u, 4); m0.h = pkmax(m0.h, t.h);
            t.u = (unsigned)__shfl_xor((int)m1.u, 4); m1.h = pkmax(m1.h, t.h);
            t.u = (unsigned)__shfl_xor((int)m2.u, 4); m2.h = pkmax(m2.h, t.h);
            t.u = (unsigned)__shfl_xor((int)m3.u, 4); m3.h = pkmax(m3.h, t.h);
            t.u = (unsigned)__shfl_xor((int)m0.u, 8); m0.h = pkmax(m0.h, t.h);
            t.u = (unsigned)__shfl_xor((int)m1.u, 8); m1.h = pkmax(m1.h, t.h);
            t.u = (unsigned)__shfl_xor((int)m2.u, 8); m2.h = pkmax(m2.h, t.h);
            t.u = (unsigned)__shfl_xor((int)m3.u, 8); m3.h = pkmax(m3.h, t.h);

            // Lane takes component es of its chunk: channels c4*8 + es*2.
            UH2 s01, s23, mm;
            s01.u = (es & 1) ? m1.u : m0.u;
            s23.u = (es & 1) ? m3.u : m2.u;
            mm.u  = (es & 2) ? s23.u : s01.u;

            unsigned int* vp = (unsigned int*)(vb + (size_t)n * SLC + cp);
            UH2 wv; wv.u = *vp;
            // empty node: mm = -inf -> a = 0 (matches segment_max empty -> 0)
            float a0 = fmaxf((float)wv.h[0] + (float)mm.h[0], 0.f);
            float a1 = fmaxf((float)wv.h[1] + (float)mm.h[1], 0.f);

            // In-place f16 agg write to the just-read v address (L1-hot).
            UH2 pw;
            pw.h[0] = (_Float16)a0;
            pw.h[1] = (_Float16)a1;
            *vp = pw.u;

            s1_0 += a0; s1_1 += a1;
            s2_0 += a0 * a0; s2_1 += a1 * a1;
        }
    };

    if (fits) gather_all([&](int i) { return (int)elds[i - s0]; });
    else      gather_all([&](int i) { return (int)edst[i]; });

    // Stats: reduce across the 16 groups; channels are disjoint per l16
    // (channel-pair = (l16&3)*8 + (l16>>2)*2).
    __syncthreads();
    red[g16][l16][0] = s1_0; red[g16][l16][1] = s1_1;
    red[g16][l16][2] = s2_0; red[g16][l16][3] = s2_1;
    __syncthreads();
    if (tid < 16) {
        const int tt = tid;
        float r0 = 0.f, r1 = 0.f, r2 = 0.f, r3 = 0.f;
        #pragma unroll
        for (int g = 0; g < 16; ++g) {
            r0 += red[g][tt][0]; r1 += red[g][tt][1];
            r2 += red[g][tt][2]; r3 += red[g][tt][3];
        }
        const int c = slice * SLC + ((tt & 3) * 8 + (tt >> 2) * 2);
        atomicAdd(&sums[c + 0], r0);
        atomicAdd(&sums[c + 1], r1);
        atomicAdd(&sumsq[c + 0], r2);
        atomicAdd(&sumsq[c + 1], r3);
    }
}

// ---------------------------------------------------------------------------
// BN + ReLU v2: reads the f16 slice-major agg (aliased onto v), writes fp32
// out node-major. Coefs computed redundantly per block in LDS. Each thread:
// one uint4 = 8 f16 channels of one (slice, node) -> 2 float4 stores.
// 76.8 MB total traffic (was 102.4). Grid: 12.8M elems / 2048 = 6250 blocks.
// ---------------------------------------------------------------------------
__global__ __launch_bounds__(256) void bn_apply(
    const unsigned short* __restrict__ agg,   // [SL][N][SLC] f16 (== v)
    float* __restrict__ out, const float* __restrict__ sums,
    const float* __restrict__ sumsq, const float* __restrict__ gamma,
    const float* __restrict__ beta)
{
    __shared__ float cA[C_OUT], cB[C_OUT];
    const int tid = threadIdx.x;
    {
        const float inv_n = 1.f / (float)N_NODES;
        const float mean = sums[tid] * inv_n;
        const float var = sumsq[tid] * inv_n - mean * mean;
        const float s = rsqrtf(var + BN_EPS) * gamma[tid];
        cA[tid] = s;
        cB[tid] = beta[tid] - mean * s;
    }
    __syncthreads();

    const size_t base = (size_t)blockIdx.x * 2048 + (size_t)tid * 8;  // f16 elem idx
    const int slice  = (int)(base / ((size_t)N_NODES * SLC));
    const int within = (int)(base % ((size_t)N_NODES * SLC));
    const int n  = within >> 5;
    const int c  = slice * SLC + (within & 31);   // 8-aligned channel base

    uint4 w = *(const uint4*)(agg + base);
    const float4 A0 = *(const float4*)(cA + c);
    const float4 A1 = *(const float4*)(cA + c + 4);
    const float4 B0 = *(const float4*)(cB + c);
    const float4 B1 = *(const float4*)(cB + c + 4);

    UH2 t;
    float4 o0, o1;
    t.u = w.x;
    o0.x = fmaxf((float)t.h[0] * A0.x + B0.x, 0.f);
    o0.y = fmaxf((float)t.h[1] * A0.y + B0.y, 0.f);
    t.u = w.y;
    o0.z = fmaxf((float)t.h[0] * A0.z + B0.z, 0.f);
    o0.w = fmaxf((float)t.h[1] * A0.w + B0.w, 0.f);
    t.u = w.z;
    o1.x = fmaxf((float)t.h[0] * A1.x + B1.x, 0.f);
    o1.y = fmaxf((float)t.h[1] * A1.y + B1.y, 0.f);
    t.u = w.w;
    o1.z = fmaxf((float)t.h[0] * A1.z + B1.z, 0.f);
    o1.w = fmaxf((float)t.h[1] * A1.w + B1.w, 0.f);

    float* op = out + (size_t)n * C_OUT + c;
    *(float4*)op = o0;
    *(float4*)(op + 4) = o1;
}

extern "C" void kernel_launch(void* const* d_in, const int* in_sizes, int n_in,
                              void* d_out, int out_size, void* d_ws, size_t ws_size,
                              hipStream_t stream) {
    const float* x     = (const float*)d_in[0];
    const int*   src   = (const int*)d_in[1];
    const int*   dst   = (const int*)d_in[2];
    const float* theta = (const float*)d_in[3];
    const float* phi   = (const float*)d_in[4];
    const float* gamma = (const float*)d_in[5];
    const float* beta  = (const float*)d_in[6];
    float* out = (float*)d_out;

    // Workspace layout (16B-aligned chunks):
    char* ws = (char*)d_ws;
    const size_t uv_elems = (size_t)N_NODES * C_OUT;
    unsigned short* u = (unsigned short*)ws;                       // 25.6 MB fp16 slice-major
    unsigned short* v = u + uv_elems;                              // 25.6 MB fp16 (agg in-place)
    float* sums   = (float*)(v + uv_elems);
    float* sumsq  = sums + C_OUT;
    int*   deg    = (int*)(sumsq + C_OUT);                         // contiguous for one memset
    int*   off    = deg + N_NODES;                                 // N_NODES+1 entries
    unsigned short* rank = (unsigned short*)(off + N_NODES + 4);   // 1.6 MB ushort
    unsigned short* edst = rank + N_EDGES;                         // 1.6 MB ushort
    int*   partials = (int*)(edst + N_EDGES);                      // NBLK ints
    unsigned short* xb = (unsigned short*)(partials + NBLK + 8);   // 12.8 MB bf16
    unsigned short* wb = xb + (size_t)N_NODES * C_IN;              // 128 KB bf16

    // Zero sums/sumsq/deg in one shot (contiguous).
    hipMemsetAsync(sums, 0, (2 * C_OUT + N_NODES) * sizeof(int), stream);

    // Fused hist(+rank) + convert.
    prep<<<HB + (XQ + WQ + 255) / 256, 256, 0, stream>>>(
        x, theta, phi, src, xb, wb, deg, rank);

    scan_part<<<NBLK, 256, 0, stream>>>(deg, partials);
    scan_fin<<<NBLK, 256, 0, stream>>>(deg, partials, off);

    // Fused atomic-free scatter + MFMA GEMM.
    gemm_scatter<<<HB + GB, 256, 0, stream>>>(
        xb, wb, u, v, src, dst, off, rank, edst);

    const int chunks = (N_NODES + NPB - 1) / NPB;
    gather_slice<<<chunks * SL, 256, 0, stream>>>(
        off, edst, u, v, sums, sumsq);

    bn_apply<<<(int)(((size_t)N_NODES * C_OUT) / 2048), 256, 0, stream>>>(
        v, out, sums, sumsq, gamma, beta);
}

// Round 7
// 228.537 us; speedup vs baseline: 1.2037x; 1.0029x over previous
//
#include <hip/hip_runtime.h>

#define N_NODES 50000
#define N_EDGES 800000
#define C_IN 128
#define C_OUT 256
#define BN_EPS 1e-5f
#define NBLK ((N_NODES + 255) / 256)   // 196 scan blocks
#define SL 8                           // channel slices (== XCD count)
#define SLC 32                         // channels per slice
#define NPB 128                        // nodes per gather block (8 per 16-lane group)
#define PAD 8                          // LDS row pad (elems, keeps 16B align)
#define ECAP 3072                      // staged edges per gather block (avg 2048, 22-sigma headroom)

#define HB 782                         // hist/scatter blocks (1024 edges each)
#define GBX ((N_NODES + 127) / 128)    // 391 gemm row-tiles
#define GB (GBX * 4)                   // 1564 gemm blocks

using short8  = __attribute__((ext_vector_type(8))) short;
using floatx4 = __attribute__((ext_vector_type(4))) float;
using h2      = __attribute__((ext_vector_type(2))) _Float16;

union UH2 { unsigned int u; h2 h; };
union HS  { _Float16 f; unsigned short s; };

// packed f16 max -> v_pk_max_f16 (no header dependency; ROCm 7.2 lacks __hmax2)
__device__ __forceinline__ h2 pkmax(h2 a, h2 b) {
    return __builtin_elementwise_max(a, b);
}

// fp32 -> bf16 round-to-nearest-even (GEMM inputs only)
__device__ __forceinline__ unsigned short f2bf(float f) {
    unsigned int u = __float_as_uint(f);
    u = (u + 0x7fffu + ((u >> 16) & 1u)) >> 16;
    return (unsigned short)u;
}

#define XQ (N_NODES * C_IN / 4)        // 1,600,000 float4 of x
#define WQ (512 * C_IN / 4)            // 16,384 float4 of W'

// ---------------------------------------------------------------------------
// prep: fused [src-degree histogram + edge rank] + [convert x,W' -> bf16].
// RANK TRICK: the histogram atomicAdd's return value IS edge e's rank within
// its src segment. rank stored as ushort (max deg << 65536) — halves traffic.
// Identity: theta@(xj-xi) + phi@xi = u[dst] + v[src]; relu/max commute so
// the edge pass only needs max over u rows.
// ---------------------------------------------------------------------------
__global__ __launch_bounds__(256) void prep(
    const float* __restrict__ x, const float* __restrict__ theta,
    const float* __restrict__ phi, const int* __restrict__ src,
    unsigned short* __restrict__ xb, unsigned short* __restrict__ wb,
    int* __restrict__ deg, unsigned short* __restrict__ rank)
{
    const int tid = threadIdx.x;
    if (blockIdx.x < HB) {
        const int base = blockIdx.x * 1024 + tid;
        #pragma unroll
        for (int k = 0; k < 4; ++k) {
            int e = base + k * 256;
            if (e < N_EDGES)
                rank[e] = (unsigned short)atomicAdd(&deg[src[e]], 1);
        }
        return;
    }
    int i = (blockIdx.x - HB) * 256 + tid;
    if (i < XQ) {
        float4 vv = ((const float4*)x)[i];
        ((ushort4*)xb)[i] = make_ushort4(f2bf(vv.x), f2bf(vv.y),
                                         f2bf(vv.z), f2bf(vv.w));
    } else if (i < XQ + WQ) {
        int j = i - XQ;
        float4 t;
        if (j < 256 * C_IN / 4) {
            t = ((const float4*)theta)[j];
        } else {
            int k = j - 256 * C_IN / 4;
            float4 th = ((const float4*)theta)[k];
            float4 ph = ((const float4*)phi)[k];
            t = make_float4(ph.x - th.x, ph.y - th.y, ph.z - th.z, ph.w - th.w);
        }
        ((ushort4*)wb)[j] = make_ushort4(f2bf(t.x), f2bf(t.y),
                                         f2bf(t.z), f2bf(t.w));
    }
}

// ---------------------------------------------------------------------------
// CSR scan: per-block partial sums, then scan_fin with the 196-entry
// mid-scan done redundantly per block in LDS (kills the scan_mid launch).
// ---------------------------------------------------------------------------
__global__ __launch_bounds__(256) void scan_part(
    const int* __restrict__ deg, int* __restrict__ partials)
{
    __shared__ int s[256];
    const int tid = threadIdx.x;
    int i = blockIdx.x * 256 + tid;
    s[tid] = (i < N_NODES) ? deg[i] : 0;
    __syncthreads();
    for (int d = 128; d > 0; d >>= 1) {
        if (tid < d) s[tid] += s[tid + d];
        __syncthreads();
    }
    if (tid == 0) partials[blockIdx.x] = s[0];
}

__global__ __launch_bounds__(256) void scan_fin(
    const int* __restrict__ deg, const int* __restrict__ partials,
    int* __restrict__ off)
{
    __shared__ int s[256];
    const int tid = threadIdx.x;

    // Inline mid-scan: inclusive scan of the 196 partials, redundant/block.
    int pv = (tid < NBLK) ? partials[tid] : 0;
    s[tid] = pv;
    __syncthreads();
    for (int d = 1; d < 256; d <<= 1) {
        int t = (tid >= d) ? s[tid - d] : 0;
        __syncthreads();
        s[tid] += t;
        __syncthreads();
    }
    const int blockPrefix = (blockIdx.x == 0) ? 0 : s[blockIdx.x - 1];
    const int total = s[NBLK - 1];
    __syncthreads();

    int i = blockIdx.x * 256 + tid;
    int v = (i < N_NODES) ? deg[i] : 0;
    s[tid] = v;
    __syncthreads();
    for (int d = 1; d < 256; d <<= 1) {
        int t = (tid >= d) ? s[tid - d] : 0;
        __syncthreads();
        s[tid] += t;
        __syncthreads();
    }
    int ex = s[tid] - v + blockPrefix;
    if (i < N_NODES) off[i] = ex;
    if (blockIdx.x == 0 && tid == 0) off[N_NODES] = total;
}

// ---------------------------------------------------------------------------
// gemm_scatter v6: fused [atomic-free edge scatter] + [MFMA GEMM].
// Scatter blocks: edst[off[src[e]] + rank[e]] = (ushort)dst[e].
// GEMM blocks: A direct-from-global, B staged in 34KB LDS.
// NEW (epilogue issue fix): SWAPPED MFMA OPERANDS — acc = mfma(bfr, a, acc)
// computes D[channel][node] (same loads/LDS/MFMA count; fragment layouts are
// symmetric: bfr is a valid A-frag with m=channel, a is a valid B-frag with
// n=node). Each lane's 4 acc regs are now 4 CONSECUTIVE CHANNELS of one
// node -> pack to one 8B ushort4-f16 store. Epilogue: 16 x 8B stores/thread
// (was 64 x 2B + 4x the address VALU). Round-0/1 PMC showed both pipes idle
// with the GEMM math worth ~2.6us — the store/addressing issue rate was the
// structural cost.
// Verified layouts: A-frag A[m=lane&15][k=quad*8+j]; B-frag B[k][n=lane&15];
// C/D col(n)=lane&15, row(m)=quad*4+reg (learn_hip m89/m91).
// ---------------------------------------------------------------------------
__global__ __launch_bounds__(256) void gemm_scatter(
    const unsigned short* __restrict__ xb,   // [N,128] bf16
    const unsigned short* __restrict__ wb,   // [512,128] bf16
    unsigned short* __restrict__ u,          // [SL][N][SLC] fp16
    unsigned short* __restrict__ v,          // [SL][N][SLC] fp16
    const int* __restrict__ src, const int* __restrict__ dst,
    const int* __restrict__ off, const unsigned short* __restrict__ rank,
    unsigned short* __restrict__ edst)
{
    __shared__ unsigned short Bs[128][C_IN + PAD];
    const int tid = threadIdx.x;

    if (blockIdx.x < HB) {
        const int base = blockIdx.x * 1024 + tid;
        #pragma unroll
        for (int k = 0; k < 4; ++k) {
            int e = base + k * 256;
            if (e < N_EDGES) {
                int s = src[e];
                edst[off[s] + (int)rank[e]] = (unsigned short)dst[e];
            }
        }
        return;
    }

    const int b = blockIdx.x - HB;
    const int bx = b >> 2;
    const int by = b & 3;
    const int wave = tid >> 6;
    const int lane = tid & 63;
    const int l15 = lane & 15;
    const int quad = lane >> 4;

    // Stage B: 128 rows x 128 bf16 (2 threads/row, 8 uint4 each).
    {
        int r = tid >> 1;
        int cb = (tid & 1) * 64;
        const uint4* sp = (const uint4*)(wb + (size_t)(by * 128 + r) * C_IN + cb);
        #pragma unroll
        for (int i = 0; i < 8; ++i) *(uint4*)&Bs[r][cb + i * 8] = sp[i];
    }

    // x fragment base pointers (rows clamped; OOB nodes computed, not stored).
    const int n0 = bx * 128 + wave * 32 + l15;
    const unsigned short* arow0 = xb + (size_t)min(n0,      N_NODES - 1) * C_IN + quad * 8;
    const unsigned short* arow1 = xb + (size_t)min(n0 + 16, N_NODES - 1) * C_IN + quad * 8;

    __syncthreads();

    floatx4 acc[2][8];
    #pragma unroll
    for (int mi = 0; mi < 2; ++mi)
        #pragma unroll
        for (int ni = 0; ni < 8; ++ni)
            acc[mi][ni] = (floatx4){0.f, 0.f, 0.f, 0.f};

    #pragma unroll
    for (int ks = 0; ks < 4; ++ks) {
        short8 a[2], bfr[8];
        a[0] = *(const short8*)(arow0 + ks * 32);
        a[1] = *(const short8*)(arow1 + ks * 32);
        #pragma unroll
        for (int ni = 0; ni < 8; ++ni)
            bfr[ni] = *(const short8*)&Bs[ni * 16 + l15][ks * 32 + quad * 8];
        // SWAPPED: W' rows as A-operand, x rows as B-operand -> D[ch][node].
        #pragma unroll
        for (int mi = 0; mi < 2; ++mi)
            #pragma unroll
            for (int ni = 0; ni < 8; ++ni)
                acc[mi][ni] = __builtin_amdgcn_mfma_f32_16x16x32_bf16(
                    bfr[ni], a[mi], acc[mi][ni], 0, 0, 0);
    }

    // Epilogue: lane holds 4 consecutive channels (cb..cb+3) of node n.
    const bool is_u = (by < 2);   // 128-col tile never straddles 256
    unsigned short* dstbuf = is_u ? u : v;
    #pragma unroll
    for (int mi = 0; mi < 2; ++mi) {
        const int n = bx * 128 + wave * 32 + mi * 16 + l15;
        if (n >= N_NODES) continue;
        #pragma unroll
        for (int ni = 0; ni < 8; ++ni) {
            const int cb = by * 128 + ni * 16 + quad * 4;   // 0..511, 4-aligned
            const int s = (cb >> 5) & 7;                    // slice within u or v
            const int o = cb & 31;                          // 8B-aligned offset
            HS h0, h1, h2_, h3;
            h0.f = (_Float16)acc[mi][ni][0];
            h1.f = (_Float16)acc[mi][ni][1];
            h2_.f = (_Float16)acc[mi][ni][2];
            h3.f = (_Float16)acc[mi][ni][3];
            *(ushort4*)(dstbuf + ((size_t)s * N_NODES + n) * SLC + o) =
                make_ushort4(h0.s, h1.s, h2_.s, h3.s);
        }
    }
}

// ---------------------------------------------------------------------------
// Sliced gather-max v5. blockIdx & 7 = channel slice = XCD. One node per
// 16-lane group; lane l16 = es*4+c4 reads the c4-th 16B chunk of edge-slot
// es's u row; 16 edges/round, 4-deep MLP/lane; block-contiguous edst range
// staged in LDS (ushort: 6KB). Pre-BN aggregate relu(max_u + v) written back
// IN-PLACE into v as packed f16 (L1-hot, 4B) — v becomes the agg buffer.
// ---------------------------------------------------------------------------
__global__ __launch_bounds__(256) void gather_slice(
    const int* __restrict__ off, const unsigned short* __restrict__ edst,
    const unsigned short* __restrict__ u, unsigned short* __restrict__ v,
    float* __restrict__ sums, float* __restrict__ sumsq)
{
    __shared__ unsigned short elds[ECAP];   // 6KB staged edge-dst indices
    __shared__ int offs[NPB + 1];           // staged CSR offsets
    __shared__ float red[16][16][4];        // stats reduction

    const int slice = blockIdx.x & 7;
    const int chunk = blockIdx.x >> 3;
    const int tid = threadIdx.x;
    const int g16 = tid >> 4;           // block-level group id 0..15
    const int l16 = tid & 15;
    const int es  = l16 >> 2;           // edge slot 0..3 (lane bits 2,3)
    const int c4  = l16 & 3;            // 16B chunk within 64B row
    const int c16 = c4 * 16;            // byte offset within row
    const int cp  = c4 * 8 + es * 2;    // this thread's channel pair in slice

    const int cn   = chunk * NPB;                     // first node of chunk
    const int nend = min(cn + NPB, N_NODES);          // exclusive
    const int nloc = nend - cn;

    // Stage offs + edst range (coalesced; one barrier).
    const int s0  = off[cn];
    const int cnt = off[nend] - s0;
    for (int t = tid; t <= nloc; t += 256) offs[t] = off[cn + t];
    const bool fits = (cnt <= ECAP);
    if (fits)
        for (int t = tid; t < cnt; t += 256) elds[t] = edst[s0 + t];
    __syncthreads();

    const char* ub = (const char*)(u + (size_t)slice * N_NODES * SLC);
    unsigned short* vb = v + (size_t)slice * N_NODES * SLC;

    float s1_0 = 0.f, s1_1 = 0.f, s2_0 = 0.f, s2_1 = 0.f;

    auto gather_all = [&](auto fetch) {
        #pragma unroll 1
        for (int i = 0; i < NPB / 16; ++i) {
            const int nl = i * 16 + g16;
            const int n = cn + nl;
            if (n >= N_NODES) continue;
            const int start = offs[nl];
            const int end   = offs[nl + 1];

            UH2 m0, m1, m2, m3;
            m0.u = m1.u = m2.u = m3.u = 0xFC00FC00u;   // packed f16 -inf

            const int nit = (end - start + 15) >> 4;   // 16 edges/round
            const int lim = end - 1;
            int b16 = start + es;
            for (int r = 0; r < nit; ++r, b16 += 16) {
                int i0 = min(b16,      lim);
                int i1 = min(b16 + 4,  lim);
                int i2 = min(b16 + 8,  lim);
                int i3 = min(b16 + 12, lim);
                int d0 = fetch(i0);
                int d1 = fetch(i1);
                int d2 = fetch(i2);
                int d3 = fetch(i3);
                uint4 w0 = *(const uint4*)(ub + ((d0 << 6) | c16));
                uint4 w1 = *(const uint4*)(ub + ((d1 << 6) | c16));
                uint4 w2 = *(const uint4*)(ub + ((d2 << 6) | c16));
                uint4 w3 = *(const uint4*)(ub + ((d3 << 6) | c16));
                UH2 a_, b_, c_, e_;
                a_.u = w0.x; b_.u = w1.x; c_.u = w2.x; e_.u = w3.x;
                m0.h = pkmax(m0.h, pkmax(pkmax(a_.h, b_.h), pkmax(c_.h, e_.h)));
                a_.u = w0.y; b_.u = w1.y; c_.u = w2.y; e_.u = w3.y;
                m1.h = pkmax(m1.h, pkmax(pkmax(a_.h, b_.h), pkmax(c_.h, e_.h)));
                a_.u = w0.z; b_.u = w1.z; c_.u = w2.z; e_.u = w3.z;
                m2.h = pkmax(m2.h, pkmax(pkmax(a_.h, b_.h), pkmax(c_.h, e_.h)));
                a_.u = w0.w; b_.u = w1.w; c_.u = w2.w; e_.u = w3.w;
                m3.h = pkmax(m3.h, pkmax(pkmax(a_.h, b_.h), pkmax(c_.h, e_.h)));
            }

            // Butterfly max across the 4 edge-slot lanes (lane bits 2, 3).
            UH2 t;
            t.u = (unsigned)__shfl_xor((int)m0.u, 4); m0.h = pkmax(m0.h, t.h);
            t.u = (unsigned)__shfl_xor((int)m1.u, 4); m1.h = pkmax(m1.h, t.h);
            t.u = (unsigned)__shfl_xor((int)m2.u, 4); m2.h = pkmax(m2.h, t.h);
            t.u = (unsigned)__shfl_xor((int)m3.u, 4); m3.h = pkmax(m3.h, t.h);
            t.u = (unsigned)__shfl_xor((int)m0.u, 8); m0.h = pkmax(m0.h, t.h);
            t.u = (unsigned)__shfl_xor((int)m1.u, 8); m1.h = pkmax(m1.h, t.h);
            t.u = (unsigned)__shfl_xor((int)m2.u, 8); m2.h = pkmax(m2.h, t.h);
            t.u = (unsigned)__shfl_xor((int)m3.u, 8); m3.h = pkmax(m3.h, t.h);

            // Lane takes component es of its chunk: channels c4*8 + es*2.
            UH2 s01, s23, mm;
            s01.u = (es & 1) ? m1.u : m0.u;
            s23.u = (es & 1) ? m3.u : m2.u;
            mm.u  = (es & 2) ? s23.u : s01.u;

            unsigned int* vp = (unsigned int*)(vb + (size_t)n * SLC + cp);
            UH2 wv; wv.u = *vp;
            // empty node: mm = -inf -> a = 0 (matches segment_max empty -> 0)
            float a0 = fmaxf((float)wv.h[0] + (float)mm.h[0], 0.f);
            float a1 = fmaxf((float)wv.h[1] + (float)mm.h[1], 0.f);

            // In-place f16 agg write to the just-read v address (L1-hot).
            UH2 pw;
            pw.h[0] = (_Float16)a0;
            pw.h[1] = (_Float16)a1;
            *vp = pw.u;

            s1_0 += a0; s1_1 += a1;
            s2_0 += a0 * a0; s2_1 += a1 * a1;
        }
    };

    if (fits) gather_all([&](int i) { return (int)elds[i - s0]; });
    else      gather_all([&](int i) { return (int)edst[i]; });

    // Stats: reduce across the 16 groups; channels are disjoint per l16
    // (channel-pair = (l16&3)*8 + (l16>>2)*2).
    __syncthreads();
    red[g16][l16][0] = s1_0; red[g16][l16][1] = s1_1;
    red[g16][l16][2] = s2_0; red[g16][l16][3] = s2_1;
    __syncthreads();
    if (tid < 16) {
        const int tt = tid;
        float r0 = 0.f, r1 = 0.f, r2 = 0.f, r3 = 0.f;
        #pragma unroll
        for (int g = 0; g < 16; ++g) {
            r0 += red[g][tt][0]; r1 += red[g][tt][1];
            r2 += red[g][tt][2]; r3 += red[g][tt][3];
        }
        const int c = slice * SLC + ((tt & 3) * 8 + (tt >> 2) * 2);
        atomicAdd(&sums[c + 0], r0);
        atomicAdd(&sums[c + 1], r1);
        atomicAdd(&sumsq[c + 0], r2);
        atomicAdd(&sumsq[c + 1], r3);
    }
}

// ---------------------------------------------------------------------------
// BN + ReLU v2: reads the f16 slice-major agg (aliased onto v), writes fp32
// out node-major. Coefs computed redundantly per block in LDS. Each thread:
// one uint4 = 8 f16 channels of one (slice, node) -> 2 float4 stores.
// 76.8 MB total traffic. Grid: 12.8M elems / 2048 = 6250 blocks.
// ---------------------------------------------------------------------------
__global__ __launch_bounds__(256) void bn_apply(
    const unsigned short* __restrict__ agg,   // [SL][N][SLC] f16 (== v)
    float* __restrict__ out, const float* __restrict__ sums,
    const float* __restrict__ sumsq, const float* __restrict__ gamma,
    const float* __restrict__ beta)
{
    __shared__ float cA[C_OUT], cB[C_OUT];
    const int tid = threadIdx.x;
    {
        const float inv_n = 1.f / (float)N_NODES;
        const float mean = sums[tid] * inv_n;
        const float var = sumsq[tid] * inv_n - mean * mean;
        const float s = rsqrtf(var + BN_EPS) * gamma[tid];
        cA[tid] = s;
        cB[tid] = beta[tid] - mean * s;
    }
    __syncthreads();

    const size_t base = (size_t)blockIdx.x * 2048 + (size_t)tid * 8;  // f16 elem idx
    const int slice  = (int)(base / ((size_t)N_NODES * SLC));
    const int within = (int)(base % ((size_t)N_NODES * SLC));
    const int n  = within >> 5;
    const int c  = slice * SLC + (within & 31);   // 8-aligned channel base

    uint4 w = *(const uint4*)(agg + base);
    const float4 A0 = *(const float4*)(cA + c);
    const float4 A1 = *(const float4*)(cA + c + 4);
    const float4 B0 = *(const float4*)(cB + c);
    const float4 B1 = *(const float4*)(cB + c + 4);

    UH2 t;
    float4 o0, o1;
    t.u = w.x;
    o0.x = fmaxf((float)t.h[0] * A0.x + B0.x, 0.f);
    o0.y = fmaxf((float)t.h[1] * A0.y + B0.y, 0.f);
    t.u = w.y;
    o0.z = fmaxf((float)t.h[0] * A0.z + B0.z, 0.f);
    o0.w = fmaxf((float)t.h[1] * A0.w + B0.w, 0.f);
    t.u = w.z;
    o1.x = fmaxf((float)t.h[0] * A1.x + B1.x, 0.f);
    o1.y = fmaxf((float)t.h[1] * A1.y + B1.y, 0.f);
    t.u = w.w;
    o1.z = fmaxf((float)t.h[0] * A1.z + B1.z, 0.f);
    o1.w = fmaxf((float)t.h[1] * A1.w + B1.w, 0.f);

    float* op = out + (size_t)n * C_OUT + c;
    *(float4*)op = o0;
    *(float4*)(op + 4) = o1;
}

extern "C" void kernel_launch(void* const* d_in, const int* in_sizes, int n_in,
                              void* d_out, int out_size, void* d_ws, size_t ws_size,
                              hipStream_t stream) {
    const float* x     = (const float*)d_in[0];
    const int*   src   = (const int*)d_in[1];
    const int*   dst   = (const int*)d_in[2];
    const float* theta = (const float*)d_in[3];
    const float* phi   = (const float*)d_in[4];
    const float* gamma = (const float*)d_in[5];
    const float* beta  = (const float*)d_in[6];
    float* out = (float*)d_out;

    // Workspace layout (16B-aligned chunks):
    char* ws = (char*)d_ws;
    const size_t uv_elems = (size_t)N_NODES * C_OUT;
    unsigned short* u = (unsigned short*)ws;                       // 25.6 MB fp16 slice-major
    unsigned short* v = u + uv_elems;                              // 25.6 MB fp16 (agg in-place)
    float* sums   = (float*)(v + uv_elems);
    float* sumsq  = sums + C_OUT;
    int*   deg    = (int*)(sumsq + C_OUT);                         // contiguous for one memset
    int*   off    = deg + N_NODES;                                 // N_NODES+1 entries
    unsigned short* rank = (unsigned short*)(off + N_NODES + 4);   // 1.6 MB ushort
    unsigned short* edst = rank + N_EDGES;                         // 1.6 MB ushort
    int*   partials = (int*)(edst + N_EDGES);                      // NBLK ints
    unsigned short* xb = (unsigned short*)(partials + NBLK + 8);   // 12.8 MB bf16
    unsigned short* wb = xb + (size_t)N_NODES * C_IN;              // 128 KB bf16

    // Zero sums/sumsq/deg in one shot (contiguous).
    hipMemsetAsync(sums, 0, (2 * C_OUT + N_NODES) * sizeof(int), stream);

    // Fused hist(+rank) + convert.
    prep<<<HB + (XQ + WQ + 255) / 256, 256, 0, stream>>>(
        x, theta, phi, src, xb, wb, deg, rank);

    scan_part<<<NBLK, 256, 0, stream>>>(deg, partials);
    scan_fin<<<NBLK, 256, 0, stream>>>(deg, partials, off);

    // Fused atomic-free scatter + MFMA GEMM (swapped-operand epilogue).
    gemm_scatter<<<HB + GB, 256, 0, stream>>>(
        xb, wb, u, v, src, dst, off, rank, edst);

    const int chunks = (N_NODES + NPB - 1) / NPB;
    gather_slice<<<chunks * SL, 256, 0, stream>>>(
        off, edst, u, v, sums, sumsq);

    bn_apply<<<(int)(((size_t)N_NODES * C_OUT) / 2048), 256, 0, stream>>>(
        v, out, sums, sumsq, gamma, beta);
}

// Round 8
// 226.052 us; speedup vs baseline: 1.2170x; 1.0110x over previous
//
#include <hip/hip_runtime.h>

#define N_NODES 50000
#define N_EDGES 800000
#define C_IN 128
#define C_OUT 256
#define BN_EPS 1e-5f
#define NBLK ((N_NODES + 255) / 256)   // 196 scan blocks
#define SL 8                           // channel slices (== XCD count)
#define SLC 32                         // channels per slice
#define NPB 128                        // nodes per gather block (8 per 16-lane group)
#define PAD 8                          // LDS row pad (elems, keeps 16B align)
#define ECAP 3072                      // staged edges per gather block (avg 2048, 22-sigma headroom)

#define HB 782                         // hist/scatter blocks (1024 edges each)
#define GBX ((N_NODES + 127) / 128)    // 391 gemm row-tiles
#define GB (GBX * 8)                   // 3128 gemm blocks (128 nodes x 64 cols each)

using short8  = __attribute__((ext_vector_type(8))) short;
using floatx4 = __attribute__((ext_vector_type(4))) float;
using h2      = __attribute__((ext_vector_type(2))) _Float16;

union UH2 { unsigned int u; h2 h; };
union HS  { _Float16 f; unsigned short s; };

// packed f16 max -> v_pk_max_f16 (no header dependency; ROCm 7.2 lacks __hmax2)
__device__ __forceinline__ h2 pkmax(h2 a, h2 b) {
    return __builtin_elementwise_max(a, b);
}

// fp32 -> bf16 round-to-nearest-even (GEMM inputs only)
__device__ __forceinline__ unsigned short f2bf(float f) {
    unsigned int u = __float_as_uint(f);
    u = (u + 0x7fffu + ((u >> 16) & 1u)) >> 16;
    return (unsigned short)u;
}

#define XQ (N_NODES * C_IN / 4)        // 1,600,000 float4 of x
#define WQ (512 * C_IN / 4)            // 16,384 float4 of W'

// ---------------------------------------------------------------------------
// prep: fused [src-degree histogram + edge rank] + [convert x,W' -> bf16].
// RANK TRICK: the histogram atomicAdd's return value IS edge e's rank within
// its src segment. rank stored as ushort (max deg << 65536) — halves traffic.
// Identity: theta@(xj-xi) + phi@xi = u[dst] + v[src]; relu/max commute so
// the edge pass only needs max over u rows.
// ---------------------------------------------------------------------------
__global__ __launch_bounds__(256) void prep(
    const float* __restrict__ x, const float* __restrict__ theta,
    const float* __restrict__ phi, const int* __restrict__ src,
    unsigned short* __restrict__ xb, unsigned short* __restrict__ wb,
    int* __restrict__ deg, unsigned short* __restrict__ rank)
{
    const int tid = threadIdx.x;
    if (blockIdx.x < HB) {
        const int base = blockIdx.x * 1024 + tid;
        #pragma unroll
        for (int k = 0; k < 4; ++k) {
            int e = base + k * 256;
            if (e < N_EDGES)
                rank[e] = (unsigned short)atomicAdd(&deg[src[e]], 1);
        }
        return;
    }
    int i = (blockIdx.x - HB) * 256 + tid;
    if (i < XQ) {
        float4 vv = ((const float4*)x)[i];
        ((ushort4*)xb)[i] = make_ushort4(f2bf(vv.x), f2bf(vv.y),
                                         f2bf(vv.z), f2bf(vv.w));
    } else if (i < XQ + WQ) {
        int j = i - XQ;
        float4 t;
        if (j < 256 * C_IN / 4) {
            t = ((const float4*)theta)[j];
        } else {
            int k = j - 256 * C_IN / 4;
            float4 th = ((const float4*)theta)[k];
            float4 ph = ((const float4*)phi)[k];
            t = make_float4(ph.x - th.x, ph.y - th.y, ph.z - th.z, ph.w - th.w);
        }
        ((ushort4*)wb)[j] = make_ushort4(f2bf(t.x), f2bf(t.y),
                                         f2bf(t.z), f2bf(t.w));
    }
}

// ---------------------------------------------------------------------------
// CSR scan: per-block partial sums, then scan_fin with the 196-entry
// mid-scan done redundantly per block in LDS (kills the scan_mid launch).
// ---------------------------------------------------------------------------
__global__ __launch_bounds__(256) void scan_part(
    const int* __restrict__ deg, int* __restrict__ partials)
{
    __shared__ int s[256];
    const int tid = threadIdx.x;
    int i = blockIdx.x * 256 + tid;
    s[tid] = (i < N_NODES) ? deg[i] : 0;
    __syncthreads();
    for (int d = 128; d > 0; d >>= 1) {
        if (tid < d) s[tid] += s[tid + d];
        __syncthreads();
    }
    if (tid == 0) partials[blockIdx.x] = s[0];
}

__global__ __launch_bounds__(256) void scan_fin(
    const int* __restrict__ deg, const int* __restrict__ partials,
    int* __restrict__ off)
{
    __shared__ int s[256];
    const int tid = threadIdx.x;

    // Inline mid-scan: inclusive scan of the 196 partials, redundant/block.
    int pv = (tid < NBLK) ? partials[tid] : 0;
    s[tid] = pv;
    __syncthreads();
    for (int d = 1; d < 256; d <<= 1) {
        int t = (tid >= d) ? s[tid - d] : 0;
        __syncthreads();
        s[tid] += t;
        __syncthreads();
    }
    const int blockPrefix = (blockIdx.x == 0) ? 0 : s[blockIdx.x - 1];
    const int total = s[NBLK - 1];
    __syncthreads();

    int i = blockIdx.x * 256 + tid;
    int v = (i < N_NODES) ? deg[i] : 0;
    s[tid] = v;
    __syncthreads();
    for (int d = 1; d < 256; d <<= 1) {
        int t = (tid >= d) ? s[tid - d] : 0;
        __syncthreads();
        s[tid] += t;
        __syncthreads();
    }
    int ex = s[tid] - v + blockPrefix;
    if (i < N_NODES) off[i] = ex;
    if (blockIdx.x == 0 && tid == 0) off[N_NODES] = total;
}

// ---------------------------------------------------------------------------
// gemm_scatter v8: fused [atomic-free edge scatter] + [MFMA GEMM].
// Scatter blocks: edst[off[src[e]] + rank[e]] = (ushort)dst[e].
// GEMM blocks — OCCUPANCY FIX: round-1 PMC showed MfmaUtil 3% / VALU 3% /
// HBM 21% / Occupancy 27% — pure unhidden latency; the 34.8KB B-tile capped
// residency at 4 blocks/CU. New geometry: 128 nodes x 64 cols per block
// (Bs = 64 rows x 128 K = 17.4KB -> 8 blocks/CU, the wave cap), acc halves
// to 2x4 frags (32 VGPR). Chip-wide MFMA/load/store counts identical —
// purely a latency-hiding change. Block count 1564 -> 3128.
// Swapped operands retained: acc = mfma(bfr, a, acc) computes D[ch][node];
// lane's 4 acc regs = 4 consecutive channels of one node -> one 8B store.
// Verified layouts: A-frag A[m=lane&15][k=quad*8+j]; B-frag B[k][n=lane&15];
// C/D col(n)=lane&15, row(m)=quad*4+reg (learn_hip m89/m91).
// ---------------------------------------------------------------------------
__global__ __launch_bounds__(256) void gemm_scatter(
    const unsigned short* __restrict__ xb,   // [N,128] bf16
    const unsigned short* __restrict__ wb,   // [512,128] bf16
    unsigned short* __restrict__ u,          // [SL][N][SLC] fp16
    unsigned short* __restrict__ v,          // [SL][N][SLC] fp16
    const int* __restrict__ src, const int* __restrict__ dst,
    const int* __restrict__ off, const unsigned short* __restrict__ rank,
    unsigned short* __restrict__ edst)
{
    __shared__ unsigned short Bs[64][C_IN + PAD];   // 17.4KB
    const int tid = threadIdx.x;

    if (blockIdx.x < HB) {
        const int base = blockIdx.x * 1024 + tid;
        #pragma unroll
        for (int k = 0; k < 4; ++k) {
            int e = base + k * 256;
            if (e < N_EDGES) {
                int s = src[e];
                edst[off[s] + (int)rank[e]] = (unsigned short)dst[e];
            }
        }
        return;
    }

    const int b = blockIdx.x - HB;
    const int bx = b >> 3;        // node tile (128 nodes)
    const int by = b & 7;         // col tile (64 cols)
    const int wave = tid >> 6;
    const int lane = tid & 63;
    const int l15 = lane & 15;
    const int quad = lane >> 4;

    // Stage B: 64 rows x 128 bf16 (4 threads/row, 4 uint4 each).
    {
        int r = tid >> 2;                 // 0..63
        int q = tid & 3;                  // quarter: 32 ushorts
        const uint4* sp = (const uint4*)(wb + (size_t)(by * 64 + r) * C_IN + q * 32);
        #pragma unroll
        for (int i = 0; i < 4; ++i) *(uint4*)&Bs[r][q * 32 + i * 8] = sp[i];
    }

    // x fragment base pointers (rows clamped; OOB nodes computed, not stored).
    const int n0 = bx * 128 + wave * 32 + l15;
    const unsigned short* arow0 = xb + (size_t)min(n0,      N_NODES - 1) * C_IN + quad * 8;
    const unsigned short* arow1 = xb + (size_t)min(n0 + 16, N_NODES - 1) * C_IN + quad * 8;

    __syncthreads();

    floatx4 acc[2][4];
    #pragma unroll
    for (int mi = 0; mi < 2; ++mi)
        #pragma unroll
        for (int ni = 0; ni < 4; ++ni)
            acc[mi][ni] = (floatx4){0.f, 0.f, 0.f, 0.f};

    #pragma unroll
    for (int ks = 0; ks < 4; ++ks) {
        short8 a[2], bfr[4];
        a[0] = *(const short8*)(arow0 + ks * 32);
        a[1] = *(const short8*)(arow1 + ks * 32);
        #pragma unroll
        for (int ni = 0; ni < 4; ++ni)
            bfr[ni] = *(const short8*)&Bs[ni * 16 + l15][ks * 32 + quad * 8];
        // SWAPPED: W' rows as A-operand, x rows as B-operand -> D[ch][node].
        #pragma unroll
        for (int mi = 0; mi < 2; ++mi)
            #pragma unroll
            for (int ni = 0; ni < 4; ++ni)
                acc[mi][ni] = __builtin_amdgcn_mfma_f32_16x16x32_bf16(
                    bfr[ni], a[mi], acc[mi][ni], 0, 0, 0);
    }

    // Epilogue: lane holds 4 consecutive channels (cb..cb+3) of node n.
    const bool is_u = (by < 4);   // 64-col tile never straddles 256
    unsigned short* dstbuf = is_u ? u : v;
    #pragma unroll
    for (int mi = 0; mi < 2; ++mi) {
        const int n = bx * 128 + wave * 32 + mi * 16 + l15;
        if (n >= N_NODES) continue;
        #pragma unroll
        for (int ni = 0; ni < 4; ++ni) {
            const int cb = by * 64 + ni * 16 + quad * 4;    // 0..511, 4-aligned
            const int s = (cb >> 5) & 7;                    // slice within u or v
            const int o = cb & 31;                          // 8B-aligned offset
            HS h0, h1, h2_, h3;
            h0.f = (_Float16)acc[mi][ni][0];
            h1.f = (_Float16)acc[mi][ni][1];
            h2_.f = (_Float16)acc[mi][ni][2];
            h3.f = (_Float16)acc[mi][ni][3];
            *(ushort4*)(dstbuf + ((size_t)s * N_NODES + n) * SLC + o) =
                make_ushort4(h0.s, h1.s, h2_.s, h3.s);
        }
    }
}

// ---------------------------------------------------------------------------
// Sliced gather-max v5. blockIdx & 7 = channel slice = XCD. One node per
// 16-lane group; lane l16 = es*4+c4 reads the c4-th 16B chunk of edge-slot
// es's u row; 16 edges/round, 4-deep MLP/lane; block-contiguous edst range
// staged in LDS (ushort: 6KB). Pre-BN aggregate relu(max_u + v) written back
// IN-PLACE into v as packed f16 (L1-hot, 4B) — v becomes the agg buffer.
// ---------------------------------------------------------------------------
__global__ __launch_bounds__(256) void gather_slice(
    const int* __restrict__ off, const unsigned short* __restrict__ edst,
    const unsigned short* __restrict__ u, unsigned short* __restrict__ v,
    float* __restrict__ sums, float* __restrict__ sumsq)
{
    __shared__ unsigned short elds[ECAP];   // 6KB staged edge-dst indices
    __shared__ int offs[NPB + 1];           // staged CSR offsets
    __shared__ float red[16][16][4];        // stats reduction

    const int slice = blockIdx.x & 7;
    const int chunk = blockIdx.x >> 3;
    const int tid = threadIdx.x;
    const int g16 = tid >> 4;           // block-level group id 0..15
    const int l16 = tid & 15;
    const int es  = l16 >> 2;           // edge slot 0..3 (lane bits 2,3)
    const int c4  = l16 & 3;            // 16B chunk within 64B row
    const int c16 = c4 * 16;            // byte offset within row
    const int cp  = c4 * 8 + es * 2;    // this thread's channel pair in slice

    const int cn   = chunk * NPB;                     // first node of chunk
    const int nend = min(cn + NPB, N_NODES);          // exclusive
    const int nloc = nend - cn;

    // Stage offs + edst range (coalesced; one barrier).
    const int s0  = off[cn];
    const int cnt = off[nend] - s0;
    for (int t = tid; t <= nloc; t += 256) offs[t] = off[cn + t];
    const bool fits = (cnt <= ECAP);
    if (fits)
        for (int t = tid; t < cnt; t += 256) elds[t] = edst[s0 + t];
    __syncthreads();

    const char* ub = (const char*)(u + (size_t)slice * N_NODES * SLC);
    unsigned short* vb = v + (size_t)slice * N_NODES * SLC;

    float s1_0 = 0.f, s1_1 = 0.f, s2_0 = 0.f, s2_1 = 0.f;

    auto gather_all = [&](auto fetch) {
        #pragma unroll 1
        for (int i = 0; i < NPB / 16; ++i) {
            const int nl = i * 16 + g16;
            const int n = cn + nl;
            if (n >= N_NODES) continue;
            const int start = offs[nl];
            const int end   = offs[nl + 1];

            UH2 m0, m1, m2, m3;
            m0.u = m1.u = m2.u = m3.u = 0xFC00FC00u;   // packed f16 -inf

            const int nit = (end - start + 15) >> 4;   // 16 edges/round
            const int lim = end - 1;
            int b16 = start + es;
            for (int r = 0; r < nit; ++r, b16 += 16) {
                int i0 = min(b16,      lim);
                int i1 = min(b16 + 4,  lim);
                int i2 = min(b16 + 8,  lim);
                int i3 = min(b16 + 12, lim);
                int d0 = fetch(i0);
                int d1 = fetch(i1);
                int d2 = fetch(i2);
                int d3 = fetch(i3);
                uint4 w0 = *(const uint4*)(ub + ((d0 << 6) | c16));
                uint4 w1 = *(const uint4*)(ub + ((d1 << 6) | c16));
                uint4 w2 = *(const uint4*)(ub + ((d2 << 6) | c16));
                uint4 w3 = *(const uint4*)(ub + ((d3 << 6) | c16));
                UH2 a_, b_, c_, e_;
                a_.u = w0.x; b_.u = w1.x; c_.u = w2.x; e_.u = w3.x;
                m0.h = pkmax(m0.h, pkmax(pkmax(a_.h, b_.h), pkmax(c_.h, e_.h)));
                a_.u = w0.y; b_.u = w1.y; c_.u = w2.y; e_.u = w3.y;
                m1.h = pkmax(m1.h, pkmax(pkmax(a_.h, b_.h), pkmax(c_.h, e_.h)));
                a_.u = w0.z; b_.u = w1.z; c_.u = w2.z; e_.u = w3.z;
                m2.h = pkmax(m2.h, pkmax(pkmax(a_.h, b_.h), pkmax(c_.h, e_.h)));
                a_.u = w0.w; b_.u = w1.w; c_.u = w2.w; e_.u = w3.w;
                m3.h = pkmax(m3.h, pkmax(pkmax(a_.h, b_.h), pkmax(c_.h, e_.h)));
            }

            // Butterfly max across the 4 edge-slot lanes (lane bits 2, 3).
            UH2 t;
            t.u = (unsigned)__shfl_xor((int)m0.u, 4); m0.h = pkmax(m0.h, t.h);
            t.u = (unsigned)__shfl_xor((int)m1.u, 4); m1.h = pkmax(m1.h, t.h);
            t.u = (unsigned)__shfl_xor((int)m2.u, 4); m2.h = pkmax(m2.h, t.h);
            t.u = (unsigned)__shfl_xor((int)m3.u, 4); m3.h = pkmax(m3.h, t.h);
            t.u = (unsigned)__shfl_xor((int)m0.u, 8); m0.h = pkmax(m0.h, t.h);
            t.u = (unsigned)__shfl_xor((int)m1.u, 8); m1.h = pkmax(m1.h, t.h);
            t.u = (unsigned)__shfl_xor((int)m2.u, 8); m2.h = pkmax(m2.h, t.h);
            t.u = (unsigned)__shfl_xor((int)m3.u, 8); m3.h = pkmax(m3.h, t.h);

            // Lane takes component es of its chunk: channels c4*8 + es*2.
            UH2 s01, s23, mm;
            s01.u = (es & 1) ? m1.u : m0.u;
            s23.u = (es & 1) ? m3.u : m2.u;
            mm.u  = (es & 2) ? s23.u : s01.u;

            unsigned int* vp = (unsigned int*)(vb + (size_t)n * SLC + cp);
            UH2 wv; wv.u = *vp;
            // empty node: mm = -inf -> a = 0 (matches segment_max empty -> 0)
            float a0 = fmaxf((float)wv.h[0] + (float)mm.h[0], 0.f);
            float a1 = fmaxf((float)wv.h[1] + (float)mm.h[1], 0.f);

            // In-place f16 agg write to the just-read v address (L1-hot).
            UH2 pw;
            pw.h[0] = (_Float16)a0;
            pw.h[1] = (_Float16)a1;
            *vp = pw.u;

            s1_0 += a0; s1_1 += a1;
            s2_0 += a0 * a0; s2_1 += a1 * a1;
        }
    };

    if (fits) gather_all([&](int i) { return (int)elds[i - s0]; });
    else      gather_all([&](int i) { return (int)edst[i]; });

    // Stats: reduce across the 16 groups; channels are disjoint per l16
    // (channel-pair = (l16&3)*8 + (l16>>2)*2).
    __syncthreads();
    red[g16][l16][0] = s1_0; red[g16][l16][1] = s1_1;
    red[g16][l16][2] = s2_0; red[g16][l16][3] = s2_1;
    __syncthreads();
    if (tid < 16) {
        const int tt = tid;
        float r0 = 0.f, r1 = 0.f, r2 = 0.f, r3 = 0.f;
        #pragma unroll
        for (int g = 0; g < 16; ++g) {
            r0 += red[g][tt][0]; r1 += red[g][tt][1];
            r2 += red[g][tt][2]; r3 += red[g][tt][3];
        }
        const int c = slice * SLC + ((tt & 3) * 8 + (tt >> 2) * 2);
        atomicAdd(&sums[c + 0], r0);
        atomicAdd(&sums[c + 1], r1);
        atomicAdd(&sumsq[c + 0], r2);
        atomicAdd(&sumsq[c + 1], r3);
    }
}

// ---------------------------------------------------------------------------
// BN + ReLU v2: reads the f16 slice-major agg (aliased onto v), writes fp32
// out node-major. Coefs computed redundantly per block in LDS. Each thread:
// one uint4 = 8 f16 channels of one (slice, node) -> 2 float4 stores.
// 76.8 MB total traffic. Grid: 12.8M elems / 2048 = 6250 blocks.
// ---------------------------------------------------------------------------
__global__ __launch_bounds__(256) void bn_apply(
    const unsigned short* __restrict__ agg,   // [SL][N][SLC] f16 (== v)
    float* __restrict__ out, const float* __restrict__ sums,
    const float* __restrict__ sumsq, const float* __restrict__ gamma,
    const float* __restrict__ beta)
{
    __shared__ float cA[C_OUT], cB[C_OUT];
    const int tid = threadIdx.x;
    {
        const float inv_n = 1.f / (float)N_NODES;
        const float mean = sums[tid] * inv_n;
        const float var = sumsq[tid] * inv_n - mean * mean;
        const float s = rsqrtf(var + BN_EPS) * gamma[tid];
        cA[tid] = s;
        cB[tid] = beta[tid] - mean * s;
    }
    __syncthreads();

    const size_t base = (size_t)blockIdx.x * 2048 + (size_t)tid * 8;  // f16 elem idx
    const int slice  = (int)(base / ((size_t)N_NODES * SLC));
    const int within = (int)(base % ((size_t)N_NODES * SLC));
    const int n  = within >> 5;
    const int c  = slice * SLC + (within & 31);   // 8-aligned channel base

    uint4 w = *(const uint4*)(agg + base);
    const float4 A0 = *(const float4*)(cA + c);
    const float4 A1 = *(const float4*)(cA + c + 4);
    const float4 B0 = *(const float4*)(cB + c);
    const float4 B1 = *(const float4*)(cB + c + 4);

    UH2 t;
    float4 o0, o1;
    t.u = w.x;
    o0.x = fmaxf((float)t.h[0] * A0.x + B0.x, 0.f);
    o0.y = fmaxf((float)t.h[1] * A0.y + B0.y, 0.f);
    t.u = w.y;
    o0.z = fmaxf((float)t.h[0] * A0.z + B0.z, 0.f);
    o0.w = fmaxf((float)t.h[1] * A0.w + B0.w, 0.f);
    t.u = w.z;
    o1.x = fmaxf((float)t.h[0] * A1.x + B1.x, 0.f);
    o1.y = fmaxf((float)t.h[1] * A1.y + B1.y, 0.f);
    t.u = w.w;
    o1.z = fmaxf((float)t.h[0] * A1.z + B1.z, 0.f);
    o1.w = fmaxf((float)t.h[1] * A1.w + B1.w, 0.f);

    float* op = out + (size_t)n * C_OUT + c;
    *(float4*)op = o0;
    *(float4*)(op + 4) = o1;
}

extern "C" void kernel_launch(void* const* d_in, const int* in_sizes, int n_in,
                              void* d_out, int out_size, void* d_ws, size_t ws_size,
                              hipStream_t stream) {
    const float* x     = (const float*)d_in[0];
    const int*   src   = (const int*)d_in[1];
    const int*   dst   = (const int*)d_in[2];
    const float* theta = (const float*)d_in[3];
    const float* phi   = (const float*)d_in[4];
    const float* gamma = (const float*)d_in[5];
    const float* beta  = (const float*)d_in[6];
    float* out = (float*)d_out;

    // Workspace layout (16B-aligned chunks):
    char* ws = (char*)d_ws;
    const size_t uv_elems = (size_t)N_NODES * C_OUT;
    unsigned short* u = (unsigned short*)ws;                       // 25.6 MB fp16 slice-major
    unsigned short* v = u + uv_elems;                              // 25.6 MB fp16 (agg in-place)
    float* sums   = (float*)(v + uv_elems);
    float* sumsq  = sums + C_OUT;
    int*   deg    = (int*)(sumsq + C_OUT);                         // contiguous for one memset
    int*   off    = deg + N_NODES;                                 // N_NODES+1 entries
    unsigned short* rank = (unsigned short*)(off + N_NODES + 4);   // 1.6 MB ushort
    unsigned short* edst = rank + N_EDGES;                         // 1.6 MB ushort
    int*   partials = (int*)(edst + N_EDGES);                      // NBLK ints
    unsigned short* xb = (unsigned short*)(partials + NBLK + 8);   // 12.8 MB bf16
    unsigned short* wb = xb + (size_t)N_NODES * C_IN;              // 128 KB bf16

    // Zero sums/sumsq/deg in one shot (contiguous).
    hipMemsetAsync(sums, 0, (2 * C_OUT + N_NODES) * sizeof(int), stream);

    // Fused hist(+rank) + convert.
    prep<<<HB + (XQ + WQ + 255) / 256, 256, 0, stream>>>(
        x, theta, phi, src, xb, wb, deg, rank);

    scan_part<<<NBLK, 256, 0, stream>>>(deg, partials);
    scan_fin<<<NBLK, 256, 0, stream>>>(deg, partials, off);

    // Fused atomic-free scatter + MFMA GEMM (64-col tiles, 8 blocks/CU).
    gemm_scatter<<<HB + GB, 256, 0, stream>>>(
        xb, wb, u, v, src, dst, off, rank, edst);

    const int chunks = (N_NODES + NPB - 1) / NPB;
    gather_slice<<<chunks * SL, 256, 0, stream>>>(
        off, edst, u, v, sums, sumsq);

    bn_apply<<<(int)(((size_t)N_NODES * C_OUT) / 2048), 256, 0, stream>>>(
        v, out, sums, sumsq, gamma, beta);
}